// Round 1
// baseline (1012.446 us; speedup 1.0000x reference)
//
#include <hip/hip_runtime.h>

typedef unsigned short u16;
typedef __bf16 bf16x8 __attribute__((ext_vector_type(8)));
typedef float f4 __attribute__((ext_vector_type(4)));
typedef unsigned int u32x4 __attribute__((ext_vector_type(4)));

#define NX 11796480   // B*T*D = 3840*3072

__device__ __forceinline__ float bf2f(u16 u){ __bf16 h = __builtin_bit_cast(__bf16, u); return (float)h; }
__device__ __forceinline__ u16 f2bf(float f){ __bf16 h = (__bf16)f; return __builtin_bit_cast(u16, h); }

// ---------------- elementwise helpers ----------------
__global__ void k_zero(float* p, int n){
  int i = blockIdx.x*256 + threadIdx.x;
  if (i < n) p[i] = 0.f;
}

__global__ void k_cvt(const float* __restrict__ in, u16* __restrict__ out, int n){
  int i = blockIdx.x*256 + threadIdx.x;
  if (i < n) out[i] = f2bf(in[i]);
}

// pack Wq_t|Wk_t|Wv_t|Wq_s|Wk_s|Wv_s into (J=24, N=768, K=128) row-major bf16
__global__ void k_pack_wcat(const float* __restrict__ wqt, const float* __restrict__ wkt,
                            const float* __restrict__ wvt, const float* __restrict__ wqs,
                            const float* __restrict__ wks, const float* __restrict__ wvs,
                            u16* __restrict__ wcat){
  int i = blockIdx.x*256 + threadIdx.x;
  if (i >= 24*768*128) return;
  int e = i & 127;
  int n = (i >> 7) % 768;
  int j = i / (768*128);
  float v;
  if (n < 512){
    int tn = n >> 7, hh = (n >> 4) & 7, dd = n & 15;
    const float* W = (tn==0)? wqt : (tn==1)? wkt : (tn==2)? wvt : wqs;  // (H,J,d,E)
    v = W[(((hh*24 + j)*16 + dd) << 7) + e];
  } else {
    int m = n - 512;
    int tn = m >> 7, hh = (m >> 4) & 7, dd = m & 15;
    const float* W = (tn==0)? wks : wvs;                                // (H,d,E)
    v = W[((hh*16 + dd) << 7) + e];
  }
  wcat[i] = f2bf(v);
}

// ---------------- MFMA GEMM core: C[128,128] tile of A[M,K] * B[N,K]^T ----------------
// LDS rows padded to 72 bf16 (144B) -> 2-way-max bank aliasing (free).
__device__ __forceinline__ void gemm_tile(const u16* __restrict__ Ab, int lda,
                                          const u16* __restrict__ Bb, int ldb,
                                          int K, f4 acc[4][4], u16* As, u16* Bs)
{
  const int tid  = threadIdx.x;
  const int lane = tid & 63;
  const int wid  = tid >> 6;
  const int waveM = (wid >> 1) * 64;
  const int waveN = (wid & 1) * 64;
  const int quad = lane >> 4;
  const int r16  = lane & 15;
  const int lrow = tid >> 3;        // 0..31
  const int lcg  = (tid & 7) * 8;   // 0,8,...,56

  #pragma unroll
  for (int mt=0; mt<4; mt++)
    #pragma unroll
    for (int nt=0; nt<4; nt++)
      #pragma unroll
      for (int q=0; q<4; q++) acc[mt][nt][q] = 0.f;

  for (int k0 = 0; k0 < K; k0 += 64){
    __syncthreads();
    #pragma unroll
    for (int i=0; i<4; i++){
      int row = lrow + i*32;
      *(u32x4*)&As[row*72 + lcg] = *(const u32x4*)&Ab[(size_t)row*lda + k0 + lcg];
      *(u32x4*)&Bs[row*72 + lcg] = *(const u32x4*)&Bb[(size_t)row*ldb + k0 + lcg];
    }
    __syncthreads();
    #pragma unroll
    for (int kk=0; kk<2; kk++){
      bf16x8 af[4], bfr[4];
      #pragma unroll
      for (int mt=0; mt<4; mt++)
        af[mt] = *(const bf16x8*)&As[(waveM + mt*16 + r16)*72 + kk*32 + quad*8];
      #pragma unroll
      for (int nt=0; nt<4; nt++)
        bfr[nt] = *(const bf16x8*)&Bs[(waveN + nt*16 + r16)*72 + kk*32 + quad*8];
      #pragma unroll
      for (int mt=0; mt<4; mt++)
        #pragma unroll
        for (int nt=0; nt<4; nt++)
          acc[mt][nt] = __builtin_amdgcn_mfma_f32_16x16x32_bf16(af[mt], bfr[nt], acc[mt][nt], 0, 0, 0);
    }
  }
  __syncthreads();
}

// QKV: per joint j (grid.z), C[3840,768] scatter to 6 tensors (bf16)
__global__ __launch_bounds__(256)
void gemm_qkv(const u16* __restrict__ x, const u16* __restrict__ wcat,
              u16* __restrict__ qt, u16* __restrict__ kt, u16* __restrict__ vt,
              u16* __restrict__ qs, u16* __restrict__ ks, u16* __restrict__ vs)
{
  __shared__ u16 As[128*72];
  __shared__ u16 Bs[128*72];
  int m0 = blockIdx.x*128, n0 = blockIdx.y*128, j = blockIdx.z;
  f4 acc[4][4];
  gemm_tile(x + (size_t)m0*3072 + j*128, 3072,
            wcat + (size_t)j*98304 + (size_t)n0*128, 128, 128, acc, As, Bs);
  int lane = threadIdx.x & 63, wid = threadIdx.x >> 6;
  int waveM = (wid>>1)*64, waveN = (wid&1)*64;
  int quad = lane>>4, r16 = lane&15;
  #pragma unroll
  for (int mt=0; mt<4; mt++){
    #pragma unroll
    for (int reg=0; reg<4; reg++){
      int row = m0 + waveM + mt*16 + quad*4 + reg;   // bt index
      int b = row / 120, t = row % 120;
      #pragma unroll
      for (int nt=0; nt<4; nt++){
        int n = n0 + waveN + nt*16 + r16;
        u16 uv = f2bf(acc[mt][nt][reg]);
        if (n < 384){
          int tn = n >> 7, hh = (n >> 4) & 7, dd = n & 15;
          u16* base = (tn==0)? qt : (tn==1)? kt : vt;
          base[((((size_t)(b*8+hh)*24 + j)*120 + t) << 4) + dd] = uv;
        } else {
          int m2 = n - 384;
          int tn = m2 >> 7, hh = (m2 >> 4) & 7, dd = m2 & 15;
          u16* base = (tn==0)? qs : (tn==1)? ks : vs;
          base[((((size_t)row*8 + hh)*24 + j) << 4) + dd] = uv;
        }
      }
    }
  }
}

// generic projection: out fp32 = A@B^T + bias + res   (lda = ldb = K)
__global__ __launch_bounds__(256)
void gemm_proj(const u16* __restrict__ A, const u16* __restrict__ B, int K, int N,
               const float* __restrict__ bias, const float* __restrict__ res,
               float* __restrict__ out)
{
  __shared__ u16 As[128*72];
  __shared__ u16 Bs[128*72];
  int m0 = blockIdx.x*128, n0 = blockIdx.y*128;
  f4 acc[4][4];
  gemm_tile(A + (size_t)m0*K, K, B + (size_t)n0*K, K, K, acc, As, Bs);
  int lane = threadIdx.x & 63, wid = threadIdx.x >> 6;
  int waveM = (wid>>1)*64, waveN = (wid&1)*64;
  int quad = lane>>4, r16 = lane&15;
  #pragma unroll
  for (int mt=0; mt<4; mt++){
    #pragma unroll
    for (int reg=0; reg<4; reg++){
      int grow = m0 + waveM + mt*16 + quad*4 + reg;
      #pragma unroll
      for (int nt=0; nt<4; nt++){
        int gcol = n0 + waveN + nt*16 + r16;
        size_t idx = (size_t)grow*N + gcol;
        out[idx] = acc[mt][nt][reg] + bias[gcol] + res[idx];
      }
    }
  }
}

// FF1: out bf16 = relu(A@B^T + bias)
__global__ __launch_bounds__(256)
void gemm_relu(const u16* __restrict__ A, const u16* __restrict__ B, int K, int N,
               const float* __restrict__ bias, u16* __restrict__ out)
{
  __shared__ u16 As[128*72];
  __shared__ u16 Bs[128*72];
  int m0 = blockIdx.x*128, n0 = blockIdx.y*128;
  f4 acc[4][4];
  gemm_tile(A + (size_t)m0*K, K, B + (size_t)n0*K, K, K, acc, As, Bs);
  int lane = threadIdx.x & 63, wid = threadIdx.x >> 6;
  int waveM = (wid>>1)*64, waveN = (wid&1)*64;
  int quad = lane>>4, r16 = lane&15;
  #pragma unroll
  for (int mt=0; mt<4; mt++){
    #pragma unroll
    for (int reg=0; reg<4; reg++){
      int grow = m0 + waveM + mt*16 + quad*4 + reg;
      #pragma unroll
      for (int nt=0; nt<4; nt++){
        int gcol = n0 + waveN + nt*16 + r16;
        float v = acc[mt][nt][reg] + bias[gcol];
        out[(size_t)grow*N + gcol] = f2bf(v > 0.f ? v : 0.f);
      }
    }
  }
}

// ---------------- attention ----------------
// temporal: one block per (b,h,j); one thread per query row t; causal softmax
__global__ __launch_bounds__(128)
void temporal_attn(const u16* __restrict__ qt, const u16* __restrict__ kt,
                   const u16* __restrict__ vt, u16* __restrict__ ta)
{
  int blk = blockIdx.x;                 // (b*8+h)*24+j
  int b = blk / 192, rem = blk % 192;
  int h = rem / 24, j = rem % 24;
  const u16* qb = qt + (size_t)blk*1920;
  const u16* kb = kt + (size_t)blk*1920;
  const u16* vb = vt + (size_t)blk*1920;
  __shared__ float Ks[1920], Vs[1920];
  for (int i = threadIdx.x; i < 1920; i += 128){ Ks[i] = bf2f(kb[i]); Vs[i] = bf2f(vb[i]); }
  __syncthreads();
  int t = threadIdx.x;
  if (t < 120){
    float q[16];
    #pragma unroll
    for (int d2=0; d2<16; d2++) q[d2] = bf2f(qb[t*16 + d2]);
    float mx = -1e30f;
    for (int s=0; s<=t; s++){
      float dot = 0.f;
      #pragma unroll
      for (int d2=0; d2<16; d2++) dot += q[d2]*Ks[s*16+d2];
      float sc = dot * 0.25f;
      mx = fmaxf(mx, sc);
    }
    float Z = 0.f, acc[16];
    #pragma unroll
    for (int d2=0; d2<16; d2++) acc[d2] = 0.f;
    for (int s=0; s<=t; s++){
      float dot = 0.f;
      #pragma unroll
      for (int d2=0; d2<16; d2++) dot += q[d2]*Ks[s*16+d2];
      float w = __expf(dot*0.25f - mx);
      Z += w;
      #pragma unroll
      for (int d2=0; d2<16; d2++) acc[d2] += w*Vs[s*16+d2];
    }
    float inv = 1.f / Z;
    size_t base = (size_t)(b*120 + t)*3072 + h*384 + j*16;
    #pragma unroll
    for (int d2=0; d2<16; d2++) ta[base + d2] = f2bf(acc[d2]*inv);
  }
}

// spatial: one block per (b,t); thread = (h, j); softmax over 24 joints
__global__ __launch_bounds__(192)
void spatial_attn(const u16* __restrict__ qs, const u16* __restrict__ ks,
                  const u16* __restrict__ vs, u16* __restrict__ sa)
{
  int bt = blockIdx.x;
  size_t base = (size_t)bt * 3072;
  __shared__ float Ks[3072], Vs[3072];
  for (int i = threadIdx.x; i < 3072; i += 192){ Ks[i] = bf2f(ks[base+i]); Vs[i] = bf2f(vs[base+i]); }
  __syncthreads();
  int h = threadIdx.x / 24, j = threadIdx.x % 24;
  float q[16];
  #pragma unroll
  for (int d2=0; d2<16; d2++) q[d2] = bf2f(qs[base + h*384 + j*16 + d2]);
  float sc[24], mx = -1e30f;
  #pragma unroll
  for (int kk=0; kk<24; kk++){
    float dot = 0.f;
    #pragma unroll
    for (int d2=0; d2<16; d2++) dot += q[d2]*Ks[h*384 + kk*16 + d2];
    sc[kk] = dot * 0.25f;
    mx = fmaxf(mx, sc[kk]);
  }
  float Z = 0.f, acc[16];
  #pragma unroll
  for (int d2=0; d2<16; d2++) acc[d2] = 0.f;
  #pragma unroll
  for (int kk=0; kk<24; kk++){
    float w = __expf(sc[kk] - mx);
    Z += w;
    #pragma unroll
    for (int d2=0; d2<16; d2++) acc[d2] += w*Vs[h*384 + kk*16 + d2];
  }
  float inv = 1.f / Z;
  #pragma unroll
  for (int d2=0; d2<16; d2++) sa[base + h*384 + j*16 + d2] = f2bf(acc[d2]*inv);
}

// ---------------- batchnorm ----------------
__global__ void bn_stats(const float* __restrict__ Y, float* __restrict__ acc){
  int c = blockIdx.x*256 + threadIdx.x;       // 12 blocks * 256 = 3072 channels
  int r0 = blockIdx.y*128;                    // 30 row chunks
  float s = 0.f, s2 = 0.f;
  for (int r = r0; r < r0+128; r++){
    float v = Y[(size_t)r*3072 + c];
    s += v; s2 += v*v;
  }
  atomicAdd(&acc[c], s);
  atomicAdd(&acc[3072 + c], s2);
}

__global__ void bn_coef(const float* __restrict__ acc, const float* __restrict__ g,
                        const float* __restrict__ b, float* __restrict__ coef){
  int c = blockIdx.x*256 + threadIdx.x;
  float mean = acc[c] * (1.f/3840.f);
  float var  = acc[3072+c] * (1.f/3840.f) - mean*mean;
  float sc = g[c] * rsqrtf(var + 1e-5f);
  coef[c] = sc;
  coef[3072+c] = b[c] - mean*sc;
}

__global__ void bn_apply2(const float* __restrict__ Yt, const float* __restrict__ Ys,
                          const float* __restrict__ ct, const float* __restrict__ cs,
                          float* __restrict__ attF, u16* __restrict__ attB){
  int c = blockIdx.x*256 + threadIdx.x;
  size_t idx = (size_t)blockIdx.y*3072 + c;
  float a = Yt[idx]*ct[c] + ct[3072+c] + Ys[idx]*cs[c] + cs[3072+c];
  attF[idx] = a;
  attB[idx] = f2bf(a);
}

__global__ void bn_out(const float* __restrict__ Yf, const float* __restrict__ cf,
                       float* __restrict__ out){
  int c = blockIdx.x*256 + threadIdx.x;
  size_t idx = (size_t)blockIdx.y*3072 + c;
  out[idx] = Yf[idx]*cf[c] + cf[3072+c];
}

// ---------------- launch ----------------
extern "C" void kernel_launch(void* const* d_in, const int* in_sizes, int n_in,
                              void* d_out, int out_size, void* d_ws, size_t ws_size,
                              hipStream_t stream)
{
  const float* src  = (const float*)d_in[0];
  const float* Wq_t = (const float*)d_in[1];
  const float* Wk_t = (const float*)d_in[2];
  const float* Wv_t = (const float*)d_in[3];
  const float* Wp_t = (const float*)d_in[4];
  const float* bp_t = (const float*)d_in[5];
  const float* g_t  = (const float*)d_in[6];
  const float* b_t  = (const float*)d_in[7];
  const float* Wq_s = (const float*)d_in[8];
  const float* Wk_s = (const float*)d_in[9];
  const float* Wv_s = (const float*)d_in[10];
  const float* Wp_s = (const float*)d_in[11];
  const float* bp_s = (const float*)d_in[12];
  const float* g_s  = (const float*)d_in[13];
  const float* b_s  = (const float*)d_in[14];
  const float* W1   = (const float*)d_in[15];
  const float* b1   = (const float*)d_in[16];
  const float* W2   = (const float*)d_in[17];
  const float* b2   = (const float*)d_in[18];
  const float* g_f  = (const float*)d_in[19];
  const float* b_f  = (const float*)d_in[20];

  char* ws = (char*)d_ws;
  u16* x_bf  = (u16*)(ws + 0ull);              // 23,592,960 B
  u16* wptb  = (u16*)(ws + 23592960ull);       // 18,874,368
  u16* wpsb  = (u16*)(ws + 42467328ull);       // 18,874,368
  u16* w1b   = (u16*)(ws + 61341696ull);       //  1,572,864
  u16* w2b   = (u16*)(ws + 62914560ull);       //  1,572,864
  u16* wcat  = (u16*)(ws + 64487424ull);       //  4,718,592
  u16* qt    = (u16*)(ws + 69206016ull);       //  6 x 23,592,960
  u16* kt    = qt + NX;
  u16* vt    = kt + NX;
  u16* qs    = vt + NX;
  u16* ks    = qs + NX;
  u16* vs    = ks + NX;
  u16* tab   = (u16*)(ws + 210763776ull);      // 23,592,960
  u16* sab   = (u16*)(ws + 234356736ull);      // 23,592,960
  float* accT = (float*)(ws + 257949696ull);   // 6 x 24,576 B (acc_t/s/f + coef_t/s/f)
  float* accS = accT + 6144;
  float* accF = accS + 6144;
  float* cT   = accF + 6144;
  float* cS   = cT + 6144;
  float* cF   = cS + 6144;
  // aliases over dead regions
  float* Yt   = (float*)(ws + 69206016ull);    // over qt+kt (dead after temporal_attn)
  float* Ys   = Yt + NX;                       // over vt+qs
  float* attF = Ys + NX;                       // over ks+vs
  u16*   attB = x_bf;                          // x_bf dead after gemm_qkv
  u16*   h1   = wcat;                          // wcat dead after gemm_qkv
  float* Yf   = (float*)(ws + 210763776ull);   // over tab+sab (dead after projections)
  float* out  = (float*)d_out;

  // 1. zero BN accumulators (ws is poisoned each call)
  k_zero<<<72, 256, 0, stream>>>(accT, 18432);
  // 2. dtype conversions
  k_cvt<<<46080, 256, 0, stream>>>(src,  x_bf, NX);
  k_cvt<<<36864, 256, 0, stream>>>(Wp_t, wptb, 9437184);
  k_cvt<<<36864, 256, 0, stream>>>(Wp_s, wpsb, 9437184);
  k_cvt<<<3072,  256, 0, stream>>>(W1,   w1b,  786432);
  k_cvt<<<3072,  256, 0, stream>>>(W2,   w2b,  786432);
  k_pack_wcat<<<9216, 256, 0, stream>>>(Wq_t, Wk_t, Wv_t, Wq_s, Wk_s, Wv_s, wcat);
  // 3. QKV projections (per joint)
  gemm_qkv<<<dim3(30,6,24), 256, 0, stream>>>(x_bf, wcat, qt, kt, vt, qs, ks, vs);
  // 4. attention
  temporal_attn<<<6144, 128, 0, stream>>>(qt, kt, vt, tab);
  spatial_attn<<<3840, 192, 0, stream>>>(qs, ks, vs, sab);
  // 5. output projections + residual
  gemm_proj<<<dim3(30,24), 256, 0, stream>>>(tab, wptb, 3072, 3072, bp_t, src, Yt);
  gemm_proj<<<dim3(30,24), 256, 0, stream>>>(sab, wpsb, 3072, 3072, bp_s, src, Ys);
  // 6. BN(t) + BN(s), att = sum
  bn_stats<<<dim3(12,30), 256, 0, stream>>>(Yt, accT);
  bn_stats<<<dim3(12,30), 256, 0, stream>>>(Ys, accS);
  bn_coef<<<12, 256, 0, stream>>>(accT, g_t, b_t, cT);
  bn_coef<<<12, 256, 0, stream>>>(accS, g_s, b_s, cS);
  bn_apply2<<<dim3(12,3840), 256, 0, stream>>>(Yt, Ys, cT, cS, attF, attB);
  // 7. feed-forward
  gemm_relu<<<dim3(30,2), 256, 0, stream>>>(attB, w1b, 3072, 256, b1, h1);
  gemm_proj<<<dim3(30,24), 256, 0, stream>>>(h1, w2b, 256, 3072, b2, attF, Yf);
  // 8. final BN
  bn_stats<<<dim3(12,30), 256, 0, stream>>>(Yf, accF);
  bn_coef<<<12, 256, 0, stream>>>(accF, g_f, b_f, cF);
  bn_out<<<dim3(12,3840), 256, 0, stream>>>(Yf, cF, out);
}

// Round 2
// 956.732 us; speedup vs baseline: 1.0582x; 1.0582x over previous
//
#include <hip/hip_runtime.h>

typedef unsigned short u16;
typedef __bf16 bf16x8 __attribute__((ext_vector_type(8)));
typedef float f4 __attribute__((ext_vector_type(4)));

#define NX 11796480   // B*T*D = 3840*3072
#define LDP 136       // padded LDS row (u16 elems) for P / Vt in temporal attn

__device__ __forceinline__ float bf2f(u16 u){ __bf16 h = __builtin_bit_cast(__bf16, u); return (float)h; }
__device__ __forceinline__ u16 f2bf(float f){ __bf16 h = (__bf16)f; return __builtin_bit_cast(u16, h); }

__device__ __forceinline__ void gload_lds16(const u16* g, u16* l){
  __builtin_amdgcn_global_load_lds((const __attribute__((address_space(1))) void*)g,
                                   (__attribute__((address_space(3))) void*)l, 16, 0, 0);
}

// ---------------- elementwise helpers ----------------
__global__ void k_zero(float* p, int n){
  int i = blockIdx.x*256 + threadIdx.x;
  if (i < n) p[i] = 0.f;
}

__global__ void k_cvt(const float* __restrict__ in, u16* __restrict__ out, int n){
  int i = blockIdx.x*256 + threadIdx.x;
  if (i < n) out[i] = f2bf(in[i]);
}

// pack Wq_t|Wk_t|Wv_t|Wq_s|Wk_s|Wv_s into (J=24, N=768, K=128) row-major bf16
__global__ void k_pack_wcat(const float* __restrict__ wqt, const float* __restrict__ wkt,
                            const float* __restrict__ wvt, const float* __restrict__ wqs,
                            const float* __restrict__ wks, const float* __restrict__ wvs,
                            u16* __restrict__ wcat){
  int i = blockIdx.x*256 + threadIdx.x;
  if (i >= 24*768*128) return;
  int e = i & 127;
  int n = (i >> 7) % 768;
  int j = i / (768*128);
  float v;
  if (n < 512){
    int tn = n >> 7, hh = (n >> 4) & 7, dd = n & 15;
    const float* W = (tn==0)? wqt : (tn==1)? wkt : (tn==2)? wvt : wqs;  // (H,J,d,E)
    v = W[(((hh*24 + j)*16 + dd) << 7) + e];
  } else {
    int m = n - 512;
    int tn = m >> 7, hh = (m >> 4) & 7, dd = m & 15;
    const float* W = (tn==0)? wks : wvs;                                // (H,d,E)
    v = W[((hh*16 + dd) << 7) + e];
  }
  wcat[i] = f2bf(v);
}

// ---------------- MFMA GEMM core (m97 style): C[128,128] tile of A[M,K]*B[N,K]^T ----------------
// Unpadded 128x64 LDS tiles staged via global_load_lds width=16 (lane-ordered dest).
__device__ __forceinline__ void gemm_tile(const u16* __restrict__ Ab, int lda,
                                          const u16* __restrict__ Bb, int ldb,
                                          int K, f4 acc[4][4], u16* As, u16* Bs)
{
  const int tid  = threadIdx.x;
  const int lane = tid & 63;
  const int wid  = tid >> 6;
  const int waveM = (wid >> 1) * 64;
  const int waveN = (wid & 1) * 64;
  const int quad = lane >> 4;
  const int r16  = lane & 15;
  const int srow = tid >> 3;        // 0..31
  const int scol = (tid & 7) * 8;   // element col: 0,8,...,56

  #pragma unroll
  for (int mt=0; mt<4; mt++)
    #pragma unroll
    for (int nt=0; nt<4; nt++)
      #pragma unroll
      for (int q=0; q<4; q++) acc[mt][nt][q] = 0.f;

  for (int k0 = 0; k0 < K; k0 += 64){
    __syncthreads();
    #pragma unroll
    for (int i=0; i<4; i++){
      int row = srow + i*32;
      // LDS slot = row*64 + scol = tid*8 + i*2048 elems == wave base (wid*512+i*2048) + lane*8
      gload_lds16(&Ab[(size_t)row*lda + k0 + scol], As + wid*512 + i*2048);
      gload_lds16(&Bb[(size_t)row*ldb + k0 + scol], Bs + wid*512 + i*2048);
    }
    __builtin_amdgcn_s_waitcnt(0);
    __syncthreads();
    #pragma unroll
    for (int kk=0; kk<2; kk++){
      bf16x8 af[4], bfr[4];
      #pragma unroll
      for (int mt=0; mt<4; mt++)
        af[mt] = *(const bf16x8*)&As[(waveM + mt*16 + r16)*64 + kk*32 + quad*8];
      #pragma unroll
      for (int nt=0; nt<4; nt++)
        bfr[nt] = *(const bf16x8*)&Bs[(waveN + nt*16 + r16)*64 + kk*32 + quad*8];
      #pragma unroll
      for (int mt=0; mt<4; mt++)
        #pragma unroll
        for (int nt=0; nt<4; nt++)
          acc[mt][nt] = __builtin_amdgcn_mfma_f32_16x16x32_bf16(af[mt], bfr[nt], acc[mt][nt], 0, 0, 0);
    }
  }
  __syncthreads();
}

// QKV: per joint j (grid.z), C[3840,768] scatter to 6 tensors (bf16)
__global__ __launch_bounds__(256)
void gemm_qkv(const u16* __restrict__ x, const u16* __restrict__ wcat,
              u16* __restrict__ qt, u16* __restrict__ kt, u16* __restrict__ vt,
              u16* __restrict__ qs, u16* __restrict__ ks, u16* __restrict__ vs)
{
  __shared__ __align__(16) u16 As[128*64];
  __shared__ __align__(16) u16 Bs[128*64];
  int m0 = blockIdx.x*128, n0 = blockIdx.y*128, j = blockIdx.z;
  f4 acc[4][4];
  gemm_tile(x + (size_t)m0*3072 + j*128, 3072,
            wcat + (size_t)j*98304 + (size_t)n0*128, 128, 128, acc, As, Bs);
  int lane = threadIdx.x & 63, wid = threadIdx.x >> 6;
  int waveM = (wid>>1)*64, waveN = (wid&1)*64;
  int quad = lane>>4, r16 = lane&15;
  #pragma unroll
  for (int mt=0; mt<4; mt++){
    #pragma unroll
    for (int reg=0; reg<4; reg++){
      int row = m0 + waveM + mt*16 + quad*4 + reg;   // bt index
      int b = row / 120, t = row % 120;
      #pragma unroll
      for (int nt=0; nt<4; nt++){
        int n = n0 + waveN + nt*16 + r16;
        u16 uv = f2bf(acc[mt][nt][reg]);
        if (n < 384){
          int tn = n >> 7, hh = (n >> 4) & 7, dd = n & 15;
          u16* base = (tn==0)? qt : (tn==1)? kt : vt;
          base[((((size_t)(b*8+hh)*24 + j)*120 + t) << 4) + dd] = uv;
        } else {
          int m2 = n - 384;
          int tn = m2 >> 7, hh = (m2 >> 4) & 7, dd = m2 & 15;
          u16* base = (tn==0)? qs : (tn==1)? ks : vs;
          base[((((size_t)row*8 + hh)*24 + j) << 4) + dd] = uv;
        }
      }
    }
  }
}

// generic projection: out fp32 = A@B^T + bias + res   (lda = ldb = K)
__global__ __launch_bounds__(256)
void gemm_proj(const u16* __restrict__ A, const u16* __restrict__ B, int K, int N,
               const float* __restrict__ bias, const float* __restrict__ res,
               float* __restrict__ out)
{
  __shared__ __align__(16) u16 As[128*64];
  __shared__ __align__(16) u16 Bs[128*64];
  int m0 = blockIdx.x*128, n0 = blockIdx.y*128;
  f4 acc[4][4];
  gemm_tile(A + (size_t)m0*K, K, B + (size_t)n0*K, K, K, acc, As, Bs);
  int lane = threadIdx.x & 63, wid = threadIdx.x >> 6;
  int waveM = (wid>>1)*64, waveN = (wid&1)*64;
  int quad = lane>>4, r16 = lane&15;
  #pragma unroll
  for (int mt=0; mt<4; mt++){
    #pragma unroll
    for (int reg=0; reg<4; reg++){
      int grow = m0 + waveM + mt*16 + quad*4 + reg;
      #pragma unroll
      for (int nt=0; nt<4; nt++){
        int gcol = n0 + waveN + nt*16 + r16;
        size_t idx = (size_t)grow*N + gcol;
        out[idx] = acc[mt][nt][reg] + bias[gcol] + res[idx];
      }
    }
  }
}

// FF1: out bf16 = relu(A@B^T + bias)
__global__ __launch_bounds__(256)
void gemm_relu(const u16* __restrict__ A, const u16* __restrict__ B, int K, int N,
               const float* __restrict__ bias, u16* __restrict__ out)
{
  __shared__ __align__(16) u16 As[128*64];
  __shared__ __align__(16) u16 Bs[128*64];
  int m0 = blockIdx.x*128, n0 = blockIdx.y*128;
  f4 acc[4][4];
  gemm_tile(A + (size_t)m0*K, K, B + (size_t)n0*K, K, K, acc, As, Bs);
  int lane = threadIdx.x & 63, wid = threadIdx.x >> 6;
  int waveM = (wid>>1)*64, waveN = (wid&1)*64;
  int quad = lane>>4, r16 = lane&15;
  #pragma unroll
  for (int mt=0; mt<4; mt++){
    #pragma unroll
    for (int reg=0; reg<4; reg++){
      int grow = m0 + waveM + mt*16 + quad*4 + reg;
      #pragma unroll
      for (int nt=0; nt<4; nt++){
        int gcol = n0 + waveN + nt*16 + r16;
        float v = acc[mt][nt][reg] + bias[gcol];
        out[(size_t)grow*N + gcol] = f2bf(v > 0.f ? v : 0.f);
      }
    }
  }
}

// ---------------- temporal attention, MFMA flash-style ----------------
// One block (256 thr, 4 waves) per (b,h,j). T=120 padded to 128, d=16 padded to 32 (K of QK mfma).
__global__ __launch_bounds__(256)
void temporal_attn_mfma(const u16* __restrict__ qt, const u16* __restrict__ kt,
                        const u16* __restrict__ vt, u16* __restrict__ ta)
{
  __shared__ __align__(16) u16 P[128*LDP];
  __shared__ __align__(16) u16 Vt[16*LDP];
  int blk = blockIdx.x;                 // (b*8+h)*24+j
  int b = blk / 192, rem = blk % 192;
  int h = rem / 24, j = rem % 24;
  const u16* qb = qt + (size_t)blk*1920;
  const u16* kb = kt + (size_t)blk*1920;
  const u16* vb = vt + (size_t)blk*1920;
  int tid = threadIdx.x, lane = tid & 63, wid = tid >> 6;
  int quad = lane >> 4, r16 = lane & 15;

  // stage V transposed into LDS: Vt[d][s], s padded 120..127 = 0
  for (int e = tid; e < 1920; e += 256){
    int s = e >> 4, dd = e & 15;
    Vt[dd*LDP + s] = vb[e];
  }
  if (tid < 128){ int dd = tid >> 3, s = 120 + (tid & 7); Vt[dd*LDP + s] = 0; }
  __syncthreads();

  bf16x8 zv;
  #pragma unroll
  for (int i=0;i<8;i++) zv[i] = (__bf16)0.f;

  const int m0 = wid * 32;              // wave owns rows m0..m0+31 (2 m-tiles)
  // Q fragments: A[m=r16][k=quad*8+i], k real for quad<2 (d=16), zero-pad quad>=2
  bf16x8 qf[2];
  #pragma unroll
  for (int mt=0; mt<2; mt++){
    int row = m0 + mt*16 + r16; if (row > 119) row = 119;
    qf[mt] = (quad < 2) ? *(const bf16x8*)&qb[row*16 + (quad&1)*8] : zv;
  }

  // S = Q K^T  (scores in registers: 2 m-tiles x 8 n-tiles)
  f4 S[2][8];
  #pragma unroll
  for (int nt=0; nt<8; nt++){
    int col = nt*16 + r16; int colc = col > 119 ? 119 : col;
    bf16x8 kf = (quad < 2) ? *(const bf16x8*)&kb[colc*16 + (quad&1)*8] : zv;
    #pragma unroll
    for (int mt=0; mt<2; mt++){
      f4 zz = {0.f, 0.f, 0.f, 0.f};
      S[mt][nt] = __builtin_amdgcn_mfma_f32_16x16x32_bf16(qf[mt], kf, zz, 0, 0, 0);
    }
  }

  // scale + causal mask
  #pragma unroll
  for (int mt=0; mt<2; mt++)
    #pragma unroll
    for (int nt=0; nt<8; nt++)
      #pragma unroll
      for (int reg=0; reg<4; reg++){
        int c = nt*16 + r16;
        int r = m0 + mt*16 + quad*4 + reg;
        float v = S[mt][nt][reg] * 0.25f;
        S[mt][nt][reg] = (c > r || c >= 120) ? -1e30f : v;
      }

  // row softmax (rows live across the 16 lanes of a quad)
  float Zr[2][4];
  #pragma unroll
  for (int mt=0; mt<2; mt++)
    #pragma unroll
    for (int reg=0; reg<4; reg++){
      float m = -1e30f;
      #pragma unroll
      for (int nt=0; nt<8; nt++) m = fmaxf(m, S[mt][nt][reg]);
      #pragma unroll
      for (int off=1; off<16; off<<=1) m = fmaxf(m, __shfl_xor(m, off, 16));
      float z = 0.f;
      #pragma unroll
      for (int nt=0; nt<8; nt++){
        float e = __expf(S[mt][nt][reg] - m);
        S[mt][nt][reg] = e;
        z += e;
      }
      #pragma unroll
      for (int off=1; off<16; off<<=1) z += __shfl_xor(z, off, 16);
      Zr[mt][reg] = z;
    }

  // write P (unnormalized, bf16) to LDS in row-major [row][s]
  #pragma unroll
  for (int mt=0; mt<2; mt++)
    #pragma unroll
    for (int nt=0; nt<8; nt++)
      #pragma unroll
      for (int reg=0; reg<4; reg++)
        P[(m0 + mt*16 + quad*4 + reg)*LDP + nt*16 + r16] = f2bf(S[mt][nt][reg]);
  __syncthreads();

  // O = P V : A-frag from P rows, B-frag from Vt rows (V^T), K-tiles of 32 over s
  f4 O[2];
  #pragma unroll
  for (int mt=0; mt<2; mt++){ O[mt][0]=0.f; O[mt][1]=0.f; O[mt][2]=0.f; O[mt][3]=0.f; }
  #pragma unroll
  for (int kt8=0; kt8<4; kt8++){
    bf16x8 vf = *(const bf16x8*)&Vt[r16*LDP + kt8*32 + quad*8];
    #pragma unroll
    for (int mt=0; mt<2; mt++){
      bf16x8 pf = *(const bf16x8*)&P[(m0 + mt*16 + r16)*LDP + kt8*32 + quad*8];
      O[mt] = __builtin_amdgcn_mfma_f32_16x16x32_bf16(pf, vf, O[mt], 0, 0, 0);
    }
  }

  // store: row = m0+mt*16+quad*4+reg -> t ; col r16 = d
  #pragma unroll
  for (int mt=0; mt<2; mt++)
    #pragma unroll
    for (int reg=0; reg<4; reg++){
      int r = m0 + mt*16 + quad*4 + reg;
      if (r < 120){
        size_t idx = (size_t)(b*120 + r)*3072 + h*384 + j*16 + r16;
        ta[idx] = f2bf(O[mt][reg] / Zr[mt][reg]);
      }
    }
}

// spatial: one block per (b,t); thread = (h, j); softmax over 24 joints
__global__ __launch_bounds__(192)
void spatial_attn(const u16* __restrict__ qs, const u16* __restrict__ ks,
                  const u16* __restrict__ vs, u16* __restrict__ sa)
{
  int bt = blockIdx.x;
  size_t base = (size_t)bt * 3072;
  __shared__ float Ks[3072], Vs[3072];
  for (int i = threadIdx.x; i < 3072; i += 192){ Ks[i] = bf2f(ks[base+i]); Vs[i] = bf2f(vs[base+i]); }
  __syncthreads();
  int h = threadIdx.x / 24, j = threadIdx.x % 24;
  float q[16];
  #pragma unroll
  for (int d2=0; d2<16; d2++) q[d2] = bf2f(qs[base + h*384 + j*16 + d2]);
  float sc[24], mx = -1e30f;
  #pragma unroll
  for (int kk=0; kk<24; kk++){
    float dot = 0.f;
    #pragma unroll
    for (int d2=0; d2<16; d2++) dot += q[d2]*Ks[h*384 + kk*16 + d2];
    sc[kk] = dot * 0.25f;
    mx = fmaxf(mx, sc[kk]);
  }
  float Z = 0.f, acc[16];
  #pragma unroll
  for (int d2=0; d2<16; d2++) acc[d2] = 0.f;
  #pragma unroll
  for (int kk=0; kk<24; kk++){
    float w = __expf(sc[kk] - mx);
    Z += w;
    #pragma unroll
    for (int d2=0; d2<16; d2++) acc[d2] += w*Vs[h*384 + kk*16 + d2];
  }
  float inv = 1.f / Z;
  #pragma unroll
  for (int d2=0; d2<16; d2++) sa[base + h*384 + j*16 + d2] = f2bf(acc[d2]*inv);
}

// ---------------- batchnorm ----------------
__global__ void bn_stats(const float* __restrict__ Y, float* __restrict__ acc){
  int c = blockIdx.x*256 + threadIdx.x;       // 12 blocks * 256 = 3072 channels
  int r0 = blockIdx.y*128;                    // 30 row chunks
  float s = 0.f, s2 = 0.f;
  for (int r = r0; r < r0+128; r++){
    float v = Y[(size_t)r*3072 + c];
    s += v; s2 += v*v;
  }
  atomicAdd(&acc[c], s);
  atomicAdd(&acc[3072 + c], s2);
}

__global__ void bn_coef(const float* __restrict__ acc, const float* __restrict__ g,
                        const float* __restrict__ b, float* __restrict__ coef){
  int c = blockIdx.x*256 + threadIdx.x;
  float mean = acc[c] * (1.f/3840.f);
  float var  = acc[3072+c] * (1.f/3840.f) - mean*mean;
  float sc = g[c] * rsqrtf(var + 1e-5f);
  coef[c] = sc;
  coef[3072+c] = b[c] - mean*sc;
}

__global__ void bn_apply2(const float* __restrict__ Yt, const float* __restrict__ Ys,
                          const float* __restrict__ ct, const float* __restrict__ cs,
                          float* __restrict__ attF, u16* __restrict__ attB){
  int c = blockIdx.x*256 + threadIdx.x;
  size_t idx = (size_t)blockIdx.y*3072 + c;
  float a = Yt[idx]*ct[c] + ct[3072+c] + Ys[idx]*cs[c] + cs[3072+c];
  attF[idx] = a;
  attB[idx] = f2bf(a);
}

__global__ void bn_out(const float* __restrict__ Yf, const float* __restrict__ cf,
                       float* __restrict__ out){
  int c = blockIdx.x*256 + threadIdx.x;
  size_t idx = (size_t)blockIdx.y*3072 + c;
  out[idx] = Yf[idx]*cf[c] + cf[3072+c];
}

// ---------------- launch ----------------
extern "C" void kernel_launch(void* const* d_in, const int* in_sizes, int n_in,
                              void* d_out, int out_size, void* d_ws, size_t ws_size,
                              hipStream_t stream)
{
  const float* src  = (const float*)d_in[0];
  const float* Wq_t = (const float*)d_in[1];
  const float* Wk_t = (const float*)d_in[2];
  const float* Wv_t = (const float*)d_in[3];
  const float* Wp_t = (const float*)d_in[4];
  const float* bp_t = (const float*)d_in[5];
  const float* g_t  = (const float*)d_in[6];
  const float* b_t  = (const float*)d_in[7];
  const float* Wq_s = (const float*)d_in[8];
  const float* Wk_s = (const float*)d_in[9];
  const float* Wv_s = (const float*)d_in[10];
  const float* Wp_s = (const float*)d_in[11];
  const float* bp_s = (const float*)d_in[12];
  const float* g_s  = (const float*)d_in[13];
  const float* b_s  = (const float*)d_in[14];
  const float* W1   = (const float*)d_in[15];
  const float* b1   = (const float*)d_in[16];
  const float* W2   = (const float*)d_in[17];
  const float* b2   = (const float*)d_in[18];
  const float* g_f  = (const float*)d_in[19];
  const float* b_f  = (const float*)d_in[20];

  char* ws = (char*)d_ws;
  u16* x_bf  = (u16*)(ws + 0ull);              // 23,592,960 B
  u16* wptb  = (u16*)(ws + 23592960ull);       // 18,874,368
  u16* wpsb  = (u16*)(ws + 42467328ull);       // 18,874,368
  u16* w1b   = (u16*)(ws + 61341696ull);       //  1,572,864
  u16* w2b   = (u16*)(ws + 62914560ull);       //  1,572,864
  u16* wcat  = (u16*)(ws + 64487424ull);       //  4,718,592
  u16* qt    = (u16*)(ws + 69206016ull);       //  6 x 23,592,960
  u16* kt    = qt + NX;
  u16* vt    = kt + NX;
  u16* qs    = vt + NX;
  u16* ks    = qs + NX;
  u16* vs    = ks + NX;
  u16* tab   = (u16*)(ws + 210763776ull);      // 23,592,960
  u16* sab   = (u16*)(ws + 234356736ull);      // 23,592,960
  float* accT = (float*)(ws + 257949696ull);   // 6 x 24,576 B
  float* accS = accT + 6144;
  float* accF = accS + 6144;
  float* cT   = accF + 6144;
  float* cS   = cT + 6144;
  float* cF   = cS + 6144;
  // aliases over dead regions
  float* Yt   = (float*)(ws + 69206016ull);    // over qt+kt (dead after temporal_attn)
  float* Ys   = Yt + NX;                       // over vt+qs
  float* attF = Ys + NX;                       // over ks+vs
  u16*   attB = x_bf;                          // x_bf dead after gemm_qkv
  u16*   h1   = wcat;                          // wcat dead after gemm_qkv
  float* Yf   = (float*)(ws + 210763776ull);   // over tab+sab (dead after projections)
  float* out  = (float*)d_out;

  // 1. zero BN accumulators (ws is poisoned each call)
  k_zero<<<72, 256, 0, stream>>>(accT, 18432);
  // 2. dtype conversions
  k_cvt<<<46080, 256, 0, stream>>>(src,  x_bf, NX);
  k_cvt<<<36864, 256, 0, stream>>>(Wp_t, wptb, 9437184);
  k_cvt<<<36864, 256, 0, stream>>>(Wp_s, wpsb, 9437184);
  k_cvt<<<3072,  256, 0, stream>>>(W1,   w1b,  786432);
  k_cvt<<<3072,  256, 0, stream>>>(W2,   w2b,  786432);
  k_pack_wcat<<<9216, 256, 0, stream>>>(Wq_t, Wk_t, Wv_t, Wq_s, Wk_s, Wv_s, wcat);
  // 3. QKV projections (per joint)
  gemm_qkv<<<dim3(30,6,24), 256, 0, stream>>>(x_bf, wcat, qt, kt, vt, qs, ks, vs);
  // 4. attention
  temporal_attn_mfma<<<6144, 256, 0, stream>>>(qt, kt, vt, tab);
  spatial_attn<<<3840, 192, 0, stream>>>(qs, ks, vs, sab);
  // 5. output projections + residual
  gemm_proj<<<dim3(30,24), 256, 0, stream>>>(tab, wptb, 3072, 3072, bp_t, src, Yt);
  gemm_proj<<<dim3(30,24), 256, 0, stream>>>(sab, wpsb, 3072, 3072, bp_s, src, Ys);
  // 6. BN(t) + BN(s), att = sum
  bn_stats<<<dim3(12,30), 256, 0, stream>>>(Yt, accT);
  bn_stats<<<dim3(12,30), 256, 0, stream>>>(Ys, accS);
  bn_coef<<<12, 256, 0, stream>>>(accT, g_t, b_t, cT);
  bn_coef<<<12, 256, 0, stream>>>(accS, g_s, b_s, cS);
  bn_apply2<<<dim3(12,3840), 256, 0, stream>>>(Yt, Ys, cT, cS, attF, attB);
  // 7. feed-forward
  gemm_relu<<<dim3(30,2), 256, 0, stream>>>(attB, w1b, 3072, 256, b1, h1);
  gemm_proj<<<dim3(30,24), 256, 0, stream>>>(h1, w2b, 256, 3072, b2, attF, Yf);
  // 8. final BN
  bn_stats<<<dim3(12,30), 256, 0, stream>>>(Yf, accF);
  bn_coef<<<12, 256, 0, stream>>>(accF, g_f, b_f, cF);
  bn_out<<<dim3(12,3840), 256, 0, stream>>>(Yf, cF, out);
}

// Round 3
// 850.707 us; speedup vs baseline: 1.1901x; 1.1246x over previous
//
#include <hip/hip_runtime.h>

typedef unsigned short u16;
typedef __bf16 bf16x8 __attribute__((ext_vector_type(8)));
typedef float f4 __attribute__((ext_vector_type(4)));

#define NX 11796480   // B*T*D = 3840*3072
#define LDP 136       // padded LDS row (u16 elems) for P / Vt in temporal attn

__device__ __forceinline__ float bf2f(u16 u){ __bf16 h = __builtin_bit_cast(__bf16, u); return (float)h; }
__device__ __forceinline__ u16 f2bf(float f){ __bf16 h = (__bf16)f; return __builtin_bit_cast(u16, h); }

__device__ __forceinline__ void gload_lds16(const u16* g, u16* l){
  __builtin_amdgcn_global_load_lds((const __attribute__((address_space(1))) void*)g,
                                   (__attribute__((address_space(3))) void*)l, 16, 0, 0);
}

// ---------------- elementwise helpers ----------------
__global__ void k_zero(float* p, int n){
  int i = blockIdx.x*256 + threadIdx.x;
  if (i < n) p[i] = 0.f;
}

__global__ void k_cvt(const float* __restrict__ in, u16* __restrict__ out, int n){
  int i = blockIdx.x*256 + threadIdx.x;
  if (i < n) out[i] = f2bf(in[i]);
}

// pack Wq_t|Wk_t|Wv_t|Wq_s|Wk_s|Wv_s into (J=24, N=768, K=128) row-major bf16
__global__ void k_pack_wcat(const float* __restrict__ wqt, const float* __restrict__ wkt,
                            const float* __restrict__ wvt, const float* __restrict__ wqs,
                            const float* __restrict__ wks, const float* __restrict__ wvs,
                            u16* __restrict__ wcat){
  int i = blockIdx.x*256 + threadIdx.x;
  if (i >= 24*768*128) return;
  int e = i & 127;
  int n = (i >> 7) % 768;
  int j = i / (768*128);
  float v;
  if (n < 512){
    int tn = n >> 7, hh = (n >> 4) & 7, dd = n & 15;
    const float* W = (tn==0)? wqt : (tn==1)? wkt : (tn==2)? wvt : wqs;  // (H,J,d,E)
    v = W[(((hh*24 + j)*16 + dd) << 7) + e];
  } else {
    int m = n - 512;
    int tn = m >> 7, hh = (m >> 4) & 7, dd = m & 15;
    const float* W = (tn==0)? wks : wvs;                                // (H,d,E)
    v = W[((hh*16 + dd) << 7) + e];
  }
  wcat[i] = f2bf(v);
}

// ---------------- MFMA GEMM core: C[128,128] tile of A[M,K]*B[N,K]^T ----------------
// global_load_lds width=16 staging with XOR-swizzled source mapping:
// LDS slot (row, c) holds global column-group c ^ (row&7)  -> ds_read_b128 is 2-way max (free).
__device__ __forceinline__ void gemm_tile(const u16* __restrict__ Ab, int lda,
                                          const u16* __restrict__ Bb, int ldb,
                                          int K, f4 acc[4][4], u16* As, u16* Bs)
{
  const int tid  = threadIdx.x;
  const int lane = tid & 63;
  const int wid  = tid >> 6;
  const int waveM = (wid >> 1) * 64;
  const int waveN = (wid & 1) * 64;
  const int quad = lane >> 4;
  const int r16  = lane & 15;
  const int srow = tid >> 3;                       // 0..31
  const int gcol = ((tid & 7) ^ (srow & 7)) * 8;   // swizzled source column

  #pragma unroll
  for (int mt=0; mt<4; mt++)
    #pragma unroll
    for (int nt=0; nt<4; nt++)
      #pragma unroll
      for (int q=0; q<4; q++) acc[mt][nt][q] = 0.f;

  for (int k0 = 0; k0 < K; k0 += 64){
    __syncthreads();
    #pragma unroll
    for (int i=0; i<4; i++){
      int row = srow + i*32;
      // dest slot = tid*8 + i*2048 elems == wave base (wid*512+i*2048) + lane*8
      gload_lds16(&Ab[(size_t)row*lda + k0 + gcol], As + wid*512 + i*2048);
      gload_lds16(&Bb[(size_t)row*ldb + k0 + gcol], Bs + wid*512 + i*2048);
    }
    __builtin_amdgcn_s_waitcnt(0);
    __syncthreads();
    #pragma unroll
    for (int kk=0; kk<2; kk++){
      bf16x8 af[4], bfr[4];
      const int soff = ((kk*4 + quad) ^ (r16 & 7)) * 8;   // swizzled read slot
      #pragma unroll
      for (int mt=0; mt<4; mt++)
        af[mt] = *(const bf16x8*)&As[(waveM + mt*16 + r16)*64 + soff];
      #pragma unroll
      for (int nt=0; nt<4; nt++)
        bfr[nt] = *(const bf16x8*)&Bs[(waveN + nt*16 + r16)*64 + soff];
      #pragma unroll
      for (int mt=0; mt<4; mt++)
        #pragma unroll
        for (int nt=0; nt<4; nt++)
          acc[mt][nt] = __builtin_amdgcn_mfma_f32_16x16x32_bf16(af[mt], bfr[nt], acc[mt][nt], 0, 0, 0);
    }
  }
  __syncthreads();
}

// QKV: per joint j (grid.z), C[3840,768] scatter to 6 tensors (bf16)
__global__ __launch_bounds__(256)
void gemm_qkv(const u16* __restrict__ x, const u16* __restrict__ wcat,
              u16* __restrict__ qt, u16* __restrict__ kt, u16* __restrict__ vt,
              u16* __restrict__ qs, u16* __restrict__ ks, u16* __restrict__ vs)
{
  __shared__ __align__(16) u16 As[128*64];
  __shared__ __align__(16) u16 Bs[128*64];
  int m0 = blockIdx.x*128, n0 = blockIdx.y*128, j = blockIdx.z;
  f4 acc[4][4];
  gemm_tile(x + (size_t)m0*3072 + j*128, 3072,
            wcat + (size_t)j*98304 + (size_t)n0*128, 128, 128, acc, As, Bs);
  int lane = threadIdx.x & 63, wid = threadIdx.x >> 6;
  int waveM = (wid>>1)*64, waveN = (wid&1)*64;
  int quad = lane>>4, r16 = lane&15;
  #pragma unroll
  for (int mt=0; mt<4; mt++){
    #pragma unroll
    for (int reg=0; reg<4; reg++){
      int row = m0 + waveM + mt*16 + quad*4 + reg;   // bt index
      int b = row / 120, t = row % 120;
      #pragma unroll
      for (int nt=0; nt<4; nt++){
        int n = n0 + waveN + nt*16 + r16;
        u16 uv = f2bf(acc[mt][nt][reg]);
        if (n < 384){
          int tn = n >> 7, hh = (n >> 4) & 7, dd = n & 15;
          u16* base = (tn==0)? qt : (tn==1)? kt : vt;
          base[((((size_t)(b*8+hh)*24 + j)*120 + t) << 4) + dd] = uv;
        } else {
          int m2 = n - 384;
          int tn = m2 >> 7, hh = (m2 >> 4) & 7, dd = m2 & 15;
          u16* base = (tn==0)? qs : (tn==1)? ks : vs;
          base[((((size_t)row*8 + hh)*24 + j) << 4) + dd] = uv;
        }
      }
    }
  }
}

// dual projection: z=0 -> Yt = tab@wptb^T + bp_t + src ; z=1 -> Ys = sab@wpsb^T + bp_s + src
__global__ __launch_bounds__(256)
void gemm_proj_dual(const u16* __restrict__ A0, const u16* __restrict__ B0, const float* __restrict__ b0,
                    const u16* __restrict__ A1, const u16* __restrict__ B1, const float* __restrict__ b1v,
                    const float* __restrict__ res, float* __restrict__ O0, float* __restrict__ O1)
{
  __shared__ __align__(16) u16 As[128*64];
  __shared__ __align__(16) u16 Bs[128*64];
  int m0 = blockIdx.x*128, n0 = blockIdx.y*128, z = blockIdx.z;
  const u16* A = z ? A1 : A0;
  const u16* B = z ? B1 : B0;
  const float* bias = z ? b1v : b0;
  float* out = z ? O1 : O0;
  f4 acc[4][4];
  gemm_tile(A + (size_t)m0*3072, 3072, B + (size_t)n0*3072, 3072, 3072, acc, As, Bs);
  int lane = threadIdx.x & 63, wid = threadIdx.x >> 6;
  int waveM = (wid>>1)*64, waveN = (wid&1)*64;
  int quad = lane>>4, r16 = lane&15;
  #pragma unroll
  for (int mt=0; mt<4; mt++){
    #pragma unroll
    for (int reg=0; reg<4; reg++){
      int grow = m0 + waveM + mt*16 + quad*4 + reg;
      #pragma unroll
      for (int nt=0; nt<4; nt++){
        int gcol = n0 + waveN + nt*16 + r16;
        size_t idx = (size_t)grow*3072 + gcol;
        out[idx] = acc[mt][nt][reg] + bias[gcol] + res[idx];
      }
    }
  }
}

// generic projection: out fp32 = A@B^T + bias + res   (lda = ldb = K)
__global__ __launch_bounds__(256)
void gemm_proj(const u16* __restrict__ A, const u16* __restrict__ B, int K, int N,
               const float* __restrict__ bias, const float* __restrict__ res,
               float* __restrict__ out)
{
  __shared__ __align__(16) u16 As[128*64];
  __shared__ __align__(16) u16 Bs[128*64];
  int m0 = blockIdx.x*128, n0 = blockIdx.y*128;
  f4 acc[4][4];
  gemm_tile(A + (size_t)m0*K, K, B + (size_t)n0*K, K, K, acc, As, Bs);
  int lane = threadIdx.x & 63, wid = threadIdx.x >> 6;
  int waveM = (wid>>1)*64, waveN = (wid&1)*64;
  int quad = lane>>4, r16 = lane&15;
  #pragma unroll
  for (int mt=0; mt<4; mt++){
    #pragma unroll
    for (int reg=0; reg<4; reg++){
      int grow = m0 + waveM + mt*16 + quad*4 + reg;
      #pragma unroll
      for (int nt=0; nt<4; nt++){
        int gcol = n0 + waveN + nt*16 + r16;
        size_t idx = (size_t)grow*N + gcol;
        out[idx] = acc[mt][nt][reg] + bias[gcol] + res[idx];
      }
    }
  }
}

// FF1: out bf16 = relu(A@B^T + bias)
__global__ __launch_bounds__(256)
void gemm_relu(const u16* __restrict__ A, const u16* __restrict__ B, int K, int N,
               const float* __restrict__ bias, u16* __restrict__ out)
{
  __shared__ __align__(16) u16 As[128*64];
  __shared__ __align__(16) u16 Bs[128*64];
  int m0 = blockIdx.x*128, n0 = blockIdx.y*128;
  f4 acc[4][4];
  gemm_tile(A + (size_t)m0*K, K, B + (size_t)n0*K, K, K, acc, As, Bs);
  int lane = threadIdx.x & 63, wid = threadIdx.x >> 6;
  int waveM = (wid>>1)*64, waveN = (wid&1)*64;
  int quad = lane>>4, r16 = lane&15;
  #pragma unroll
  for (int mt=0; mt<4; mt++){
    #pragma unroll
    for (int reg=0; reg<4; reg++){
      int grow = m0 + waveM + mt*16 + quad*4 + reg;
      #pragma unroll
      for (int nt=0; nt<4; nt++){
        int gcol = n0 + waveN + nt*16 + r16;
        float v = acc[mt][nt][reg] + bias[gcol];
        out[(size_t)grow*N + gcol] = f2bf(v > 0.f ? v : 0.f);
      }
    }
  }
}

// ---------------- temporal attention, MFMA flash-style ----------------
__global__ __launch_bounds__(256)
void temporal_attn_mfma(const u16* __restrict__ qt, const u16* __restrict__ kt,
                        const u16* __restrict__ vt, u16* __restrict__ ta)
{
  __shared__ __align__(16) u16 P[128*LDP];
  __shared__ __align__(16) u16 Vt[16*LDP];
  int blk = blockIdx.x;                 // (b*8+h)*24+j
  int b = blk / 192, rem = blk % 192;
  int h = rem / 24, j = rem % 24;
  const u16* qb = qt + (size_t)blk*1920;
  const u16* kb = kt + (size_t)blk*1920;
  const u16* vb = vt + (size_t)blk*1920;
  int tid = threadIdx.x, lane = tid & 63, wid = tid >> 6;
  int quad = lane >> 4, r16 = lane & 15;

  for (int e = tid; e < 1920; e += 256){
    int s = e >> 4, dd = e & 15;
    Vt[dd*LDP + s] = vb[e];
  }
  if (tid < 128){ int dd = tid >> 3, s = 120 + (tid & 7); Vt[dd*LDP + s] = 0; }
  __syncthreads();

  bf16x8 zv;
  #pragma unroll
  for (int i=0;i<8;i++) zv[i] = (__bf16)0.f;

  const int m0 = wid * 32;
  bf16x8 qf[2];
  #pragma unroll
  for (int mt=0; mt<2; mt++){
    int row = m0 + mt*16 + r16; if (row > 119) row = 119;
    qf[mt] = (quad < 2) ? *(const bf16x8*)&qb[row*16 + (quad&1)*8] : zv;
  }

  f4 S[2][8];
  #pragma unroll
  for (int nt=0; nt<8; nt++){
    int col = nt*16 + r16; int colc = col > 119 ? 119 : col;
    bf16x8 kf = (quad < 2) ? *(const bf16x8*)&kb[colc*16 + (quad&1)*8] : zv;
    #pragma unroll
    for (int mt=0; mt<2; mt++){
      f4 zz = {0.f, 0.f, 0.f, 0.f};
      S[mt][nt] = __builtin_amdgcn_mfma_f32_16x16x32_bf16(qf[mt], kf, zz, 0, 0, 0);
    }
  }

  #pragma unroll
  for (int mt=0; mt<2; mt++)
    #pragma unroll
    for (int nt=0; nt<8; nt++)
      #pragma unroll
      for (int reg=0; reg<4; reg++){
        int c = nt*16 + r16;
        int r = m0 + mt*16 + quad*4 + reg;
        float v = S[mt][nt][reg] * 0.25f;
        S[mt][nt][reg] = (c > r || c >= 120) ? -1e30f : v;
      }

  float Zr[2][4];
  #pragma unroll
  for (int mt=0; mt<2; mt++)
    #pragma unroll
    for (int reg=0; reg<4; reg++){
      float m = -1e30f;
      #pragma unroll
      for (int nt=0; nt<8; nt++) m = fmaxf(m, S[mt][nt][reg]);
      #pragma unroll
      for (int off=1; off<16; off<<=1) m = fmaxf(m, __shfl_xor(m, off, 16));
      float z = 0.f;
      #pragma unroll
      for (int nt=0; nt<8; nt++){
        float e = __expf(S[mt][nt][reg] - m);
        S[mt][nt][reg] = e;
        z += e;
      }
      #pragma unroll
      for (int off=1; off<16; off<<=1) z += __shfl_xor(z, off, 16);
      Zr[mt][reg] = z;
    }

  #pragma unroll
  for (int mt=0; mt<2; mt++)
    #pragma unroll
    for (int nt=0; nt<8; nt++)
      #pragma unroll
      for (int reg=0; reg<4; reg++)
        P[(m0 + mt*16 + quad*4 + reg)*LDP + nt*16 + r16] = f2bf(S[mt][nt][reg]);
  __syncthreads();

  f4 O[2];
  #pragma unroll
  for (int mt=0; mt<2; mt++){ O[mt][0]=0.f; O[mt][1]=0.f; O[mt][2]=0.f; O[mt][3]=0.f; }
  #pragma unroll
  for (int kt8=0; kt8<4; kt8++){
    bf16x8 vf = *(const bf16x8*)&Vt[r16*LDP + kt8*32 + quad*8];
    #pragma unroll
    for (int mt=0; mt<2; mt++){
      bf16x8 pf = *(const bf16x8*)&P[(m0 + mt*16 + r16)*LDP + kt8*32 + quad*8];
      O[mt] = __builtin_amdgcn_mfma_f32_16x16x32_bf16(pf, vf, O[mt], 0, 0, 0);
    }
  }

  #pragma unroll
  for (int mt=0; mt<2; mt++)
    #pragma unroll
    for (int reg=0; reg<4; reg++){
      int r = m0 + mt*16 + quad*4 + reg;
      if (r < 120){
        size_t idx = (size_t)(b*120 + r)*3072 + h*384 + j*16 + r16;
        ta[idx] = f2bf(O[mt][reg] / Zr[mt][reg]);
      }
    }
}

// spatial: one block per (b,t); thread = (h, j); softmax over 24 joints
__global__ __launch_bounds__(192)
void spatial_attn(const u16* __restrict__ qs, const u16* __restrict__ ks,
                  const u16* __restrict__ vs, u16* __restrict__ sa)
{
  int bt = blockIdx.x;
  size_t base = (size_t)bt * 3072;
  __shared__ float Ks[3072], Vs[3072];
  for (int i = threadIdx.x; i < 3072; i += 192){ Ks[i] = bf2f(ks[base+i]); Vs[i] = bf2f(vs[base+i]); }
  __syncthreads();
  int h = threadIdx.x / 24, j = threadIdx.x % 24;
  float q[16];
  #pragma unroll
  for (int d2=0; d2<16; d2++) q[d2] = bf2f(qs[base + h*384 + j*16 + d2]);
  float sc[24], mx = -1e30f;
  #pragma unroll
  for (int kk=0; kk<24; kk++){
    float dot = 0.f;
    #pragma unroll
    for (int d2=0; d2<16; d2++) dot += q[d2]*Ks[h*384 + kk*16 + d2];
    sc[kk] = dot * 0.25f;
    mx = fmaxf(mx, sc[kk]);
  }
  float Z = 0.f, acc[16];
  #pragma unroll
  for (int d2=0; d2<16; d2++) acc[d2] = 0.f;
  #pragma unroll
  for (int kk=0; kk<24; kk++){
    float w = __expf(sc[kk] - mx);
    Z += w;
    #pragma unroll
    for (int d2=0; d2<16; d2++) acc[d2] += w*Vs[h*384 + kk*16 + d2];
  }
  float inv = 1.f / Z;
  #pragma unroll
  for (int d2=0; d2<16; d2++) sa[base + h*384 + j*16 + d2] = f2bf(acc[d2]*inv);
}

// ---------------- batchnorm ----------------
__global__ void bn_stats(const float* __restrict__ Y, float* __restrict__ acc){
  int c = blockIdx.x*256 + threadIdx.x;
  int r0 = blockIdx.y*128;
  float s = 0.f, s2 = 0.f;
  for (int r = r0; r < r0+128; r++){
    float v = Y[(size_t)r*3072 + c];
    s += v; s2 += v*v;
  }
  atomicAdd(&acc[c], s);
  atomicAdd(&acc[3072 + c], s2);
}

__global__ void bn_coef(const float* __restrict__ acc, const float* __restrict__ g,
                        const float* __restrict__ b, float* __restrict__ coef){
  int c = blockIdx.x*256 + threadIdx.x;
  float mean = acc[c] * (1.f/3840.f);
  float var  = acc[3072+c] * (1.f/3840.f) - mean*mean;
  float sc = g[c] * rsqrtf(var + 1e-5f);
  coef[c] = sc;
  coef[3072+c] = b[c] - mean*sc;
}

__global__ void bn_apply2(const float* __restrict__ Yt, const float* __restrict__ Ys,
                          const float* __restrict__ ct, const float* __restrict__ cs,
                          float* __restrict__ attF, u16* __restrict__ attB){
  int c = blockIdx.x*256 + threadIdx.x;
  size_t idx = (size_t)blockIdx.y*3072 + c;
  float a = Yt[idx]*ct[c] + ct[3072+c] + Ys[idx]*cs[c] + cs[3072+c];
  attF[idx] = a;
  attB[idx] = f2bf(a);
}

__global__ void bn_out(const float* __restrict__ Yf, const float* __restrict__ cf,
                       float* __restrict__ out){
  int c = blockIdx.x*256 + threadIdx.x;
  size_t idx = (size_t)blockIdx.y*3072 + c;
  out[idx] = Yf[idx]*cf[c] + cf[3072+c];
}

// ---------------- launch ----------------
extern "C" void kernel_launch(void* const* d_in, const int* in_sizes, int n_in,
                              void* d_out, int out_size, void* d_ws, size_t ws_size,
                              hipStream_t stream)
{
  const float* src  = (const float*)d_in[0];
  const float* Wq_t = (const float*)d_in[1];
  const float* Wk_t = (const float*)d_in[2];
  const float* Wv_t = (const float*)d_in[3];
  const float* Wp_t = (const float*)d_in[4];
  const float* bp_t = (const float*)d_in[5];
  const float* g_t  = (const float*)d_in[6];
  const float* b_t  = (const float*)d_in[7];
  const float* Wq_s = (const float*)d_in[8];
  const float* Wk_s = (const float*)d_in[9];
  const float* Wv_s = (const float*)d_in[10];
  const float* Wp_s = (const float*)d_in[11];
  const float* bp_s = (const float*)d_in[12];
  const float* g_s  = (const float*)d_in[13];
  const float* b_s  = (const float*)d_in[14];
  const float* W1   = (const float*)d_in[15];
  const float* b1   = (const float*)d_in[16];
  const float* W2   = (const float*)d_in[17];
  const float* b2   = (const float*)d_in[18];
  const float* g_f  = (const float*)d_in[19];
  const float* b_f  = (const float*)d_in[20];

  char* ws = (char*)d_ws;
  u16* x_bf  = (u16*)(ws + 0ull);
  u16* wptb  = (u16*)(ws + 23592960ull);
  u16* wpsb  = (u16*)(ws + 42467328ull);
  u16* w1b   = (u16*)(ws + 61341696ull);
  u16* w2b   = (u16*)(ws + 62914560ull);
  u16* wcat  = (u16*)(ws + 64487424ull);
  u16* qt    = (u16*)(ws + 69206016ull);
  u16* kt    = qt + NX;
  u16* vt    = kt + NX;
  u16* qs    = vt + NX;
  u16* ks    = qs + NX;
  u16* vs    = ks + NX;
  u16* tab   = (u16*)(ws + 210763776ull);
  u16* sab   = (u16*)(ws + 234356736ull);
  float* accT = (float*)(ws + 257949696ull);
  float* accS = accT + 6144;
  float* accF = accS + 6144;
  float* cT   = accF + 6144;
  float* cS   = cT + 6144;
  float* cF   = cS + 6144;
  float* Yt   = (float*)(ws + 69206016ull);    // over qt+kt (dead after temporal_attn)
  float* Ys   = Yt + NX;                       // over vt+qs
  float* attF = Ys + NX;                       // over ks+vs
  u16*   attB = x_bf;
  u16*   h1   = wcat;
  float* Yf   = (float*)(ws + 210763776ull);   // over tab+sab
  float* out  = (float*)d_out;

  k_zero<<<72, 256, 0, stream>>>(accT, 18432);
  k_cvt<<<46080, 256, 0, stream>>>(src,  x_bf, NX);
  k_cvt<<<36864, 256, 0, stream>>>(Wp_t, wptb, 9437184);
  k_cvt<<<36864, 256, 0, stream>>>(Wp_s, wpsb, 9437184);
  k_cvt<<<3072,  256, 0, stream>>>(W1,   w1b,  786432);
  k_cvt<<<3072,  256, 0, stream>>>(W2,   w2b,  786432);
  k_pack_wcat<<<9216, 256, 0, stream>>>(Wq_t, Wk_t, Wv_t, Wq_s, Wk_s, Wv_s, wcat);
  gemm_qkv<<<dim3(30,6,24), 256, 0, stream>>>(x_bf, wcat, qt, kt, vt, qs, ks, vs);
  temporal_attn_mfma<<<6144, 256, 0, stream>>>(qt, kt, vt, tab);
  spatial_attn<<<3840, 192, 0, stream>>>(qs, ks, vs, sab);
  gemm_proj_dual<<<dim3(30,24,2), 256, 0, stream>>>(tab, wptb, bp_t, sab, wpsb, bp_s, src, Yt, Ys);
  bn_stats<<<dim3(12,30), 256, 0, stream>>>(Yt, accT);
  bn_stats<<<dim3(12,30), 256, 0, stream>>>(Ys, accS);
  bn_coef<<<12, 256, 0, stream>>>(accT, g_t, b_t, cT);
  bn_coef<<<12, 256, 0, stream>>>(accS, g_s, b_s, cS);
  bn_apply2<<<dim3(12,3840), 256, 0, stream>>>(Yt, Ys, cT, cS, attF, attB);
  gemm_relu<<<dim3(30,2), 256, 0, stream>>>(attB, w1b, 3072, 256, b1, h1);
  gemm_proj<<<dim3(30,24), 256, 0, stream>>>(h1, w2b, 256, 3072, b2, attF, Yf);
  bn_stats<<<dim3(12,30), 256, 0, stream>>>(Yf, accF);
  bn_coef<<<12, 256, 0, stream>>>(accF, g_f, b_f, cF);
  bn_out<<<dim3(12,3840), 256, 0, stream>>>(Yf, cF, out);
}

// Round 4
// 748.057 us; speedup vs baseline: 1.3534x; 1.1372x over previous
//
#include <hip/hip_runtime.h>

typedef unsigned short u16;
typedef __bf16 bf16x8 __attribute__((ext_vector_type(8)));
typedef float f4 __attribute__((ext_vector_type(4)));
typedef float float4v __attribute__((ext_vector_type(4)));
typedef u16 u16x4 __attribute__((ext_vector_type(4)));

#define NX 11796480   // B*T*D = 3840*3072
#define LDP 136       // padded LDS row (u16 elems) for P / Vt in temporal attn

__device__ __forceinline__ float bf2f(u16 u){ __bf16 h = __builtin_bit_cast(__bf16, u); return (float)h; }
__device__ __forceinline__ u16 f2bf(float f){ __bf16 h = (__bf16)f; return __builtin_bit_cast(u16, h); }

__device__ __forceinline__ void gload_lds16(const u16* g, u16* l){
  __builtin_amdgcn_global_load_lds((const __attribute__((address_space(1))) void*)g,
                                   (__attribute__((address_space(3))) void*)l, 16, 0, 0);
}

// ---------------- elementwise helpers ----------------
__global__ void k_zero(float* p, int n){
  int i = blockIdx.x*256 + threadIdx.x;
  if (i < n) p[i] = 0.f;
}

// vectorized fp32 -> bf16 (n multiple of 4)
__global__ void k_cvt4(const float* __restrict__ in, u16* __restrict__ out, int n4){
  int i = blockIdx.x*256 + threadIdx.x;
  if (i < n4){
    float4v v = *(const float4v*)&in[i*4];
    u16x4 o;
    o[0]=f2bf(v[0]); o[1]=f2bf(v[1]); o[2]=f2bf(v[2]); o[3]=f2bf(v[3]);
    *(u16x4*)&out[i*4] = o;
  }
}

// pack Wq_t|Wk_t|Wv_t|Wq_s|Wk_s|Wv_s into (J=24, N=768, K=128) row-major bf16
__global__ void k_pack_wcat(const float* __restrict__ wqt, const float* __restrict__ wkt,
                            const float* __restrict__ wvt, const float* __restrict__ wqs,
                            const float* __restrict__ wks, const float* __restrict__ wvs,
                            u16* __restrict__ wcat){
  int i = blockIdx.x*256 + threadIdx.x;
  if (i >= 24*768*128) return;
  int e = i & 127;
  int n = (i >> 7) % 768;
  int j = i / (768*128);
  float v;
  if (n < 512){
    int tn = n >> 7, hh = (n >> 4) & 7, dd = n & 15;
    const float* W = (tn==0)? wqt : (tn==1)? wkt : (tn==2)? wvt : wqs;  // (H,J,d,E)
    v = W[(((hh*24 + j)*16 + dd) << 7) + e];
  } else {
    int m = n - 512;
    int tn = m >> 7, hh = (m >> 4) & 7, dd = m & 15;
    const float* W = (tn==0)? wks : wvs;                                // (H,d,E)
    v = W[((hh*16 + dd) << 7) + e];
  }
  wcat[i] = f2bf(v);
}

// ---------------- MFMA GEMM core (BK=64): C[128,128] tile of A[M,K]*B[N,K]^T ----------------
// global_load_lds width=16 staging with XOR-swizzled source mapping:
// LDS slot (row, c) holds global column-group c ^ (row&7) -> ds_read_b128 2-way max (free).
__device__ __forceinline__ void gemm_tile(const u16* __restrict__ Ab, int lda,
                                          const u16* __restrict__ Bb, int ldb,
                                          int K, f4 acc[4][4], u16* As, u16* Bs)
{
  const int tid  = threadIdx.x;
  const int lane = tid & 63;
  const int wid  = tid >> 6;
  const int waveM = (wid >> 1) * 64;
  const int waveN = (wid & 1) * 64;
  const int quad = lane >> 4;
  const int r16  = lane & 15;
  const int srow = tid >> 3;                       // 0..31
  const int gcol = ((tid & 7) ^ (srow & 7)) * 8;   // swizzled source column

  #pragma unroll
  for (int mt=0; mt<4; mt++)
    #pragma unroll
    for (int nt=0; nt<4; nt++)
      #pragma unroll
      for (int q=0; q<4; q++) acc[mt][nt][q] = 0.f;

  for (int k0 = 0; k0 < K; k0 += 64){
    __syncthreads();
    #pragma unroll
    for (int i=0; i<4; i++){
      int row = srow + i*32;
      gload_lds16(&Ab[(size_t)row*lda + k0 + gcol], As + wid*512 + i*2048);
      gload_lds16(&Bb[(size_t)row*ldb + k0 + gcol], Bs + wid*512 + i*2048);
    }
    __builtin_amdgcn_s_waitcnt(0);
    __syncthreads();
    #pragma unroll
    for (int kk=0; kk<2; kk++){
      bf16x8 af[4], bfr[4];
      const int soff = ((kk*4 + quad) ^ (r16 & 7)) * 8;   // swizzled read slot
      #pragma unroll
      for (int mt=0; mt<4; mt++)
        af[mt] = *(const bf16x8*)&As[(waveM + mt*16 + r16)*64 + soff];
      #pragma unroll
      for (int nt=0; nt<4; nt++)
        bfr[nt] = *(const bf16x8*)&Bs[(waveN + nt*16 + r16)*64 + soff];
      #pragma unroll
      for (int mt=0; mt<4; mt++)
        #pragma unroll
        for (int nt=0; nt<4; nt++)
          acc[mt][nt] = __builtin_amdgcn_mfma_f32_16x16x32_bf16(af[mt], bfr[nt], acc[mt][nt], 0, 0, 0);
    }
  }
  __syncthreads();
}

// ---------------- QKV GEMM, BK=128 (K=128 exactly: single staging round) ----------------
__global__ __launch_bounds__(256)
void gemm_qkv(const u16* __restrict__ x, const u16* __restrict__ wcat,
              u16* __restrict__ qt, u16* __restrict__ kt, u16* __restrict__ vt,
              u16* __restrict__ qs, u16* __restrict__ ks, u16* __restrict__ vs)
{
  __shared__ __align__(16) u16 As[128*128];
  __shared__ __align__(16) u16 Bs[128*128];
  int m0 = blockIdx.x*128, n0 = blockIdx.y*128, j = blockIdx.z;
  const u16* Ab = x + (size_t)m0*3072 + j*128;
  const u16* Bb = wcat + (size_t)j*98304 + (size_t)n0*128;
  int tid = threadIdx.x, lane = tid & 63, wid = tid >> 6;
  int quad = lane >> 4, r16 = lane & 15;
  int srow16 = tid >> 4;                   // 0..15
  int cslot  = tid & 15;
  int gcol   = (cslot ^ srow16) * 8;       // swizzled source column (row&15 == srow16)

  #pragma unroll
  for (int it=0; it<8; it++){
    int row = srow16 + it*16;
    gload_lds16(&Ab[(size_t)row*3072 + gcol], As + tid*8 + it*2048);
    gload_lds16(&Bb[(size_t)row*128  + gcol], Bs + tid*8 + it*2048);
  }
  __builtin_amdgcn_s_waitcnt(0);
  __syncthreads();

  int waveM = (wid>>1)*64, waveN = (wid&1)*64;
  f4 acc[4][4];
  #pragma unroll
  for (int mt=0; mt<4; mt++)
    #pragma unroll
    for (int nt=0; nt<4; nt++)
      #pragma unroll
      for (int q=0; q<4; q++) acc[mt][nt][q] = 0.f;

  #pragma unroll
  for (int kk=0; kk<4; kk++){
    bf16x8 af[4], bfr[4];
    const int soff = ((kk*4 + quad) ^ r16) * 8;
    #pragma unroll
    for (int mt=0; mt<4; mt++)
      af[mt] = *(const bf16x8*)&As[(waveM + mt*16 + r16)*128 + soff];
    #pragma unroll
    for (int nt=0; nt<4; nt++)
      bfr[nt] = *(const bf16x8*)&Bs[(waveN + nt*16 + r16)*128 + soff];
    #pragma unroll
    for (int mt=0; mt<4; mt++)
      #pragma unroll
      for (int nt=0; nt<4; nt++)
        acc[mt][nt] = __builtin_amdgcn_mfma_f32_16x16x32_bf16(af[mt], bfr[nt], acc[mt][nt], 0, 0, 0);
  }

  #pragma unroll
  for (int mt=0; mt<4; mt++){
    #pragma unroll
    for (int reg=0; reg<4; reg++){
      int row = m0 + waveM + mt*16 + quad*4 + reg;   // bt index
      int b = row / 120, t = row % 120;
      #pragma unroll
      for (int nt=0; nt<4; nt++){
        int n = n0 + waveN + nt*16 + r16;
        u16 uv = f2bf(acc[mt][nt][reg]);
        if (n < 384){
          int tn = n >> 7, hh = (n >> 4) & 7, dd = n & 15;
          u16* base = (tn==0)? qt : (tn==1)? kt : vt;
          base[((((size_t)(b*8+hh)*24 + j)*120 + t) << 4) + dd] = uv;
        } else {
          int m2 = n - 384;
          int tn = m2 >> 7, hh = (m2 >> 4) & 7, dd = m2 & 15;
          u16* base = (tn==0)? qs : (tn==1)? ks : vs;
          base[((((size_t)row*8 + hh)*24 + j) << 4) + dd] = uv;
        }
      }
    }
  }
}

// ---------------- dual projection with fused BN stats ----------------
// z=0: Yt = tab@wptb^T + bp_t + res ; z=1: Ys = sab@wpsb^T + bp_s + res  (res bf16)
// writes bf16 out + atomically accumulates per-channel sum/sumsq (fp32, pre-rounding)
__global__ __launch_bounds__(256)
void gemm_proj_dual(const u16* __restrict__ A0, const u16* __restrict__ B0, const float* __restrict__ b0,
                    const u16* __restrict__ A1, const u16* __restrict__ B1, const float* __restrict__ b1v,
                    const u16* __restrict__ resb, u16* __restrict__ O0, u16* __restrict__ O1,
                    float* __restrict__ st0, float* __restrict__ st1)
{
  __shared__ __align__(16) u16 As[128*64];
  __shared__ __align__(16) u16 Bs[128*64];
  int m0 = blockIdx.x*128, n0 = blockIdx.y*128, z = blockIdx.z;
  const u16* A = z ? A1 : A0;
  const u16* B = z ? B1 : B0;
  const float* bias = z ? b1v : b0;
  u16* out = z ? O1 : O0;
  float* stp = z ? st1 : st0;
  f4 acc[4][4];
  gemm_tile(A + (size_t)m0*3072, 3072, B + (size_t)n0*3072, 3072, 3072, acc, As, Bs);
  int lane = threadIdx.x & 63, wid = threadIdx.x >> 6;
  int waveM = (wid>>1)*64, waveN = (wid&1)*64;
  int quad = lane>>4, r16 = lane&15;
  float s[4] = {0,0,0,0}, s2[4] = {0,0,0,0};
  #pragma unroll
  for (int mt=0; mt<4; mt++){
    #pragma unroll
    for (int reg=0; reg<4; reg++){
      int grow = m0 + waveM + mt*16 + quad*4 + reg;
      #pragma unroll
      for (int nt=0; nt<4; nt++){
        int gcol = n0 + waveN + nt*16 + r16;
        size_t idx = (size_t)grow*3072 + gcol;
        float v = acc[mt][nt][reg] + bias[gcol] + bf2f(resb[idx]);
        out[idx] = f2bf(v);
        s[nt] += v; s2[nt] += v*v;
      }
    }
  }
  #pragma unroll
  for (int nt=0; nt<4; nt++){
    float a = s[nt], b = s2[nt];
    a += __shfl_xor(a, 16); a += __shfl_xor(a, 32);
    b += __shfl_xor(b, 16); b += __shfl_xor(b, 32);
    if (quad == 0){
      int col = n0 + waveN + nt*16 + r16;
      atomicAdd(&stp[col], a);
      atomicAdd(&stp[3072 + col], b);
    }
  }
}

// ---------------- FF2 with fused BN stats: Yf = h1@W2^T + b2 + attB (bf16 res) ----------------
__global__ __launch_bounds__(256)
void gemm_ff2(const u16* __restrict__ A, const u16* __restrict__ B, const float* __restrict__ bias,
              const u16* __restrict__ resb, u16* __restrict__ out, float* __restrict__ stp)
{
  __shared__ __align__(16) u16 As[128*64];
  __shared__ __align__(16) u16 Bs[128*64];
  int m0 = blockIdx.x*128, n0 = blockIdx.y*128;
  f4 acc[4][4];
  gemm_tile(A + (size_t)m0*256, 256, B + (size_t)n0*256, 256, 256, acc, As, Bs);
  int lane = threadIdx.x & 63, wid = threadIdx.x >> 6;
  int waveM = (wid>>1)*64, waveN = (wid&1)*64;
  int quad = lane>>4, r16 = lane&15;
  float s[4] = {0,0,0,0}, s2[4] = {0,0,0,0};
  #pragma unroll
  for (int mt=0; mt<4; mt++){
    #pragma unroll
    for (int reg=0; reg<4; reg++){
      int grow = m0 + waveM + mt*16 + quad*4 + reg;
      #pragma unroll
      for (int nt=0; nt<4; nt++){
        int gcol = n0 + waveN + nt*16 + r16;
        size_t idx = (size_t)grow*3072 + gcol;
        float v = acc[mt][nt][reg] + bias[gcol] + bf2f(resb[idx]);
        out[idx] = f2bf(v);
        s[nt] += v; s2[nt] += v*v;
      }
    }
  }
  #pragma unroll
  for (int nt=0; nt<4; nt++){
    float a = s[nt], b = s2[nt];
    a += __shfl_xor(a, 16); a += __shfl_xor(a, 32);
    b += __shfl_xor(b, 16); b += __shfl_xor(b, 32);
    if (quad == 0){
      int col = n0 + waveN + nt*16 + r16;
      atomicAdd(&stp[col], a);
      atomicAdd(&stp[3072 + col], b);
    }
  }
}

// FF1: out bf16 = relu(A@B^T + bias)
__global__ __launch_bounds__(256)
void gemm_relu(const u16* __restrict__ A, const u16* __restrict__ B, int K, int N,
               const float* __restrict__ bias, u16* __restrict__ out)
{
  __shared__ __align__(16) u16 As[128*64];
  __shared__ __align__(16) u16 Bs[128*64];
  int m0 = blockIdx.x*128, n0 = blockIdx.y*128;
  f4 acc[4][4];
  gemm_tile(A + (size_t)m0*K, K, B + (size_t)n0*K, K, K, acc, As, Bs);
  int lane = threadIdx.x & 63, wid = threadIdx.x >> 6;
  int waveM = (wid>>1)*64, waveN = (wid&1)*64;
  int quad = lane>>4, r16 = lane&15;
  #pragma unroll
  for (int mt=0; mt<4; mt++){
    #pragma unroll
    for (int reg=0; reg<4; reg++){
      int grow = m0 + waveM + mt*16 + quad*4 + reg;
      #pragma unroll
      for (int nt=0; nt<4; nt++){
        int gcol = n0 + waveN + nt*16 + r16;
        float v = acc[mt][nt][reg] + bias[gcol];
        out[(size_t)grow*N + gcol] = f2bf(v > 0.f ? v : 0.f);
      }
    }
  }
}

// ---------------- temporal attention, MFMA flash-style ----------------
__global__ __launch_bounds__(256)
void temporal_attn_mfma(const u16* __restrict__ qt, const u16* __restrict__ kt,
                        const u16* __restrict__ vt, u16* __restrict__ ta)
{
  __shared__ __align__(16) u16 P[128*LDP];
  __shared__ __align__(16) u16 Vt[16*LDP];
  int blk = blockIdx.x;                 // (b*8+h)*24+j
  int b = blk / 192, rem = blk % 192;
  int h = rem / 24, j = rem % 24;
  const u16* qb = qt + (size_t)blk*1920;
  const u16* kb = kt + (size_t)blk*1920;
  const u16* vb = vt + (size_t)blk*1920;
  int tid = threadIdx.x, lane = tid & 63, wid = tid >> 6;
  int quad = lane >> 4, r16 = lane & 15;

  for (int e = tid; e < 1920; e += 256){
    int s = e >> 4, dd = e & 15;
    Vt[dd*LDP + s] = vb[e];
  }
  if (tid < 128){ int dd = tid >> 3, s = 120 + (tid & 7); Vt[dd*LDP + s] = 0; }
  __syncthreads();

  bf16x8 zv;
  #pragma unroll
  for (int i=0;i<8;i++) zv[i] = (__bf16)0.f;

  const int m0 = wid * 32;
  bf16x8 qf[2];
  #pragma unroll
  for (int mt=0; mt<2; mt++){
    int row = m0 + mt*16 + r16; if (row > 119) row = 119;
    qf[mt] = (quad < 2) ? *(const bf16x8*)&qb[row*16 + (quad&1)*8] : zv;
  }

  f4 S[2][8];
  #pragma unroll
  for (int nt=0; nt<8; nt++){
    int col = nt*16 + r16; int colc = col > 119 ? 119 : col;
    bf16x8 kf = (quad < 2) ? *(const bf16x8*)&kb[colc*16 + (quad&1)*8] : zv;
    #pragma unroll
    for (int mt=0; mt<2; mt++){
      f4 zz = {0.f, 0.f, 0.f, 0.f};
      S[mt][nt] = __builtin_amdgcn_mfma_f32_16x16x32_bf16(qf[mt], kf, zz, 0, 0, 0);
    }
  }

  #pragma unroll
  for (int mt=0; mt<2; mt++)
    #pragma unroll
    for (int nt=0; nt<8; nt++)
      #pragma unroll
      for (int reg=0; reg<4; reg++){
        int c = nt*16 + r16;
        int r = m0 + mt*16 + quad*4 + reg;
        float v = S[mt][nt][reg] * 0.25f;
        S[mt][nt][reg] = (c > r || c >= 120) ? -1e30f : v;
      }

  float Zr[2][4];
  #pragma unroll
  for (int mt=0; mt<2; mt++)
    #pragma unroll
    for (int reg=0; reg<4; reg++){
      float m = -1e30f;
      #pragma unroll
      for (int nt=0; nt<8; nt++) m = fmaxf(m, S[mt][nt][reg]);
      #pragma unroll
      for (int off=1; off<16; off<<=1) m = fmaxf(m, __shfl_xor(m, off, 16));
      float z = 0.f;
      #pragma unroll
      for (int nt=0; nt<8; nt++){
        float e = __expf(S[mt][nt][reg] - m);
        S[mt][nt][reg] = e;
        z += e;
      }
      #pragma unroll
      for (int off=1; off<16; off<<=1) z += __shfl_xor(z, off, 16);
      Zr[mt][reg] = z;
    }

  #pragma unroll
  for (int mt=0; mt<2; mt++)
    #pragma unroll
    for (int nt=0; nt<8; nt++)
      #pragma unroll
      for (int reg=0; reg<4; reg++)
        P[(m0 + mt*16 + quad*4 + reg)*LDP + nt*16 + r16] = f2bf(S[mt][nt][reg]);
  __syncthreads();

  f4 O[2];
  #pragma unroll
  for (int mt=0; mt<2; mt++){ O[mt][0]=0.f; O[mt][1]=0.f; O[mt][2]=0.f; O[mt][3]=0.f; }
  #pragma unroll
  for (int kt8=0; kt8<4; kt8++){
    bf16x8 vf = *(const bf16x8*)&Vt[r16*LDP + kt8*32 + quad*8];
    #pragma unroll
    for (int mt=0; mt<2; mt++){
      bf16x8 pf = *(const bf16x8*)&P[(m0 + mt*16 + r16)*LDP + kt8*32 + quad*8];
      O[mt] = __builtin_amdgcn_mfma_f32_16x16x32_bf16(pf, vf, O[mt], 0, 0, 0);
    }
  }

  #pragma unroll
  for (int mt=0; mt<2; mt++)
    #pragma unroll
    for (int reg=0; reg<4; reg++){
      int r = m0 + mt*16 + quad*4 + reg;
      if (r < 120){
        size_t idx = (size_t)(b*120 + r)*3072 + h*384 + j*16 + r16;
        ta[idx] = f2bf(O[mt][reg] / Zr[mt][reg]);
      }
    }
}

// spatial: one block per (b,t); thread = (h, j); softmax over 24 joints
__global__ __launch_bounds__(192)
void spatial_attn(const u16* __restrict__ qs, const u16* __restrict__ ks,
                  const u16* __restrict__ vs, u16* __restrict__ sa)
{
  int bt = blockIdx.x;
  size_t base = (size_t)bt * 3072;
  __shared__ float Ks[3072], Vs[3072];
  for (int i = threadIdx.x; i < 3072; i += 192){ Ks[i] = bf2f(ks[base+i]); Vs[i] = bf2f(vs[base+i]); }
  __syncthreads();
  int h = threadIdx.x / 24, j = threadIdx.x % 24;
  float q[16];
  #pragma unroll
  for (int d2=0; d2<16; d2++) q[d2] = bf2f(qs[base + h*384 + j*16 + d2]);
  float sc[24], mx = -1e30f;
  #pragma unroll
  for (int kk=0; kk<24; kk++){
    float dot = 0.f;
    #pragma unroll
    for (int d2=0; d2<16; d2++) dot += q[d2]*Ks[h*384 + kk*16 + d2];
    sc[kk] = dot * 0.25f;
    mx = fmaxf(mx, sc[kk]);
  }
  float Z = 0.f, acc[16];
  #pragma unroll
  for (int d2=0; d2<16; d2++) acc[d2] = 0.f;
  #pragma unroll
  for (int kk=0; kk<24; kk++){
    float w = __expf(sc[kk] - mx);
    Z += w;
    #pragma unroll
    for (int d2=0; d2<16; d2++) acc[d2] += w*Vs[h*384 + kk*16 + d2];
  }
  float inv = 1.f / Z;
  #pragma unroll
  for (int d2=0; d2<16; d2++) sa[base + h*384 + j*16 + d2] = f2bf(acc[d2]*inv);
}

// ---------------- batchnorm ----------------
__global__ void bn_coef(const float* __restrict__ acc, const float* __restrict__ g,
                        const float* __restrict__ b, float* __restrict__ coef){
  int c = blockIdx.x*256 + threadIdx.x;
  float mean = acc[c] * (1.f/3840.f);
  float var  = acc[3072+c] * (1.f/3840.f) - mean*mean;
  float sc = g[c] * rsqrtf(var + 1e-5f);
  coef[c] = sc;
  coef[3072+c] = b[c] - mean*sc;
}

// att = BN_t(Yt) + BN_s(Ys), bf16 in/out
__global__ void bn_apply2(const u16* __restrict__ Ytb, const u16* __restrict__ Ysb,
                          const float* __restrict__ ct, const float* __restrict__ cs,
                          u16* __restrict__ attB){
  int c = blockIdx.x*256 + threadIdx.x;
  size_t idx = (size_t)blockIdx.y*3072 + c;
  float a = bf2f(Ytb[idx])*ct[c] + ct[3072+c] + bf2f(Ysb[idx])*cs[c] + cs[3072+c];
  attB[idx] = f2bf(a);
}

__global__ void bn_out(const u16* __restrict__ Yfb, const float* __restrict__ cf,
                       float* __restrict__ out){
  int c = blockIdx.x*256 + threadIdx.x;
  size_t idx = (size_t)blockIdx.y*3072 + c;
  out[idx] = bf2f(Yfb[idx])*cf[c] + cf[3072+c];
}

// ---------------- launch ----------------
extern "C" void kernel_launch(void* const* d_in, const int* in_sizes, int n_in,
                              void* d_out, int out_size, void* d_ws, size_t ws_size,
                              hipStream_t stream)
{
  const float* src  = (const float*)d_in[0];
  const float* Wq_t = (const float*)d_in[1];
  const float* Wk_t = (const float*)d_in[2];
  const float* Wv_t = (const float*)d_in[3];
  const float* Wp_t = (const float*)d_in[4];
  const float* bp_t = (const float*)d_in[5];
  const float* g_t  = (const float*)d_in[6];
  const float* b_t  = (const float*)d_in[7];
  const float* Wq_s = (const float*)d_in[8];
  const float* Wk_s = (const float*)d_in[9];
  const float* Wv_s = (const float*)d_in[10];
  const float* Wp_s = (const float*)d_in[11];
  const float* bp_s = (const float*)d_in[12];
  const float* g_s  = (const float*)d_in[13];
  const float* b_s  = (const float*)d_in[14];
  const float* W1   = (const float*)d_in[15];
  const float* b1   = (const float*)d_in[16];
  const float* W2   = (const float*)d_in[17];
  const float* b2   = (const float*)d_in[18];
  const float* g_f  = (const float*)d_in[19];
  const float* b_f  = (const float*)d_in[20];

  char* ws = (char*)d_ws;
  u16* x_bf  = (u16*)(ws + 0ull);              // src bf16; also res for proj_dual
  u16* wptb  = (u16*)(ws + 23592960ull);
  u16* wpsb  = (u16*)(ws + 42467328ull);
  u16* w1b   = (u16*)(ws + 61341696ull);
  u16* w2b   = (u16*)(ws + 62914560ull);
  u16* wcat  = (u16*)(ws + 64487424ull);
  u16* qt    = (u16*)(ws + 69206016ull);
  u16* kt    = qt + NX;
  u16* vt    = kt + NX;
  u16* qs    = vt + NX;
  u16* ks    = qs + NX;
  u16* vs    = ks + NX;
  u16* tab   = (u16*)(ws + 210763776ull);
  u16* sab   = (u16*)(ws + 234356736ull);
  float* accT = (float*)(ws + 257949696ull);
  float* accS = accT + 6144;
  float* accF = accS + 6144;
  float* cT   = accF + 6144;
  float* cS   = cT + 6144;
  float* cF   = cS + 6144;
  // bf16 aliases over dead regions
  u16* Ytb  = qt;   // dead after temporal_attn
  u16* Ysb  = kt;   // dead after temporal_attn
  u16* attB = vt;   // dead after temporal_attn
  u16* Yfb  = qs;   // dead after spatial_attn
  u16* h1   = wcat; // dead after gemm_qkv
  float* out = (float*)d_out;

  // 1. zero BN accumulators (ws is re-poisoned each call)
  k_zero<<<72, 256, 0, stream>>>(accT, 18432);
  // 2. dtype conversions
  k_cvt4<<<11520, 256, 0, stream>>>(src,  x_bf, NX/4);
  k_cvt4<<<9216,  256, 0, stream>>>(Wp_t, wptb, 9437184/4);
  k_cvt4<<<9216,  256, 0, stream>>>(Wp_s, wpsb, 9437184/4);
  k_cvt4<<<768,   256, 0, stream>>>(W1,   w1b,  786432/4);
  k_cvt4<<<768,   256, 0, stream>>>(W2,   w2b,  786432/4);
  k_pack_wcat<<<9216, 256, 0, stream>>>(Wq_t, Wk_t, Wv_t, Wq_s, Wk_s, Wv_s, wcat);
  // 3. QKV projections (per joint, BK=128 single-round)
  gemm_qkv<<<dim3(30,6,24), 256, 0, stream>>>(x_bf, wcat, qt, kt, vt, qs, ks, vs);
  // 4. attention
  temporal_attn_mfma<<<6144, 256, 0, stream>>>(qt, kt, vt, tab);
  spatial_attn<<<3840, 192, 0, stream>>>(qs, ks, vs, sab);
  // 5. output projections + residual + fused BN stats (bf16 out)
  gemm_proj_dual<<<dim3(30,24,2), 256, 0, stream>>>(tab, wptb, bp_t, sab, wpsb, bp_s,
                                                    x_bf, Ytb, Ysb, accT, accS);
  // 6. BN coefs + fused apply (att in bf16)
  bn_coef<<<12, 256, 0, stream>>>(accT, g_t, b_t, cT);
  bn_coef<<<12, 256, 0, stream>>>(accS, g_s, b_s, cS);
  bn_apply2<<<dim3(12,3840), 256, 0, stream>>>(Ytb, Ysb, cT, cS, attB);
  // 7. feed-forward (FF2 fuses residual + BN stats)
  gemm_relu<<<dim3(30,2), 256, 0, stream>>>(attB, w1b, 3072, 256, b1, h1);
  gemm_ff2<<<dim3(30,24), 256, 0, stream>>>(h1, w2b, b2, attB, Yfb, accF);
  // 8. final BN
  bn_coef<<<12, 256, 0, stream>>>(accF, g_f, b_f, cF);
  bn_out<<<dim3(12,3840), 256, 0, stream>>>(Yfb, cF, out);
}

// Round 6
// 702.755 us; speedup vs baseline: 1.4407x; 1.0645x over previous
//
#include <hip/hip_runtime.h>

typedef unsigned short u16;
typedef __bf16 bf16x8 __attribute__((ext_vector_type(8)));
typedef float f4 __attribute__((ext_vector_type(4)));
typedef float float4v __attribute__((ext_vector_type(4)));
typedef u16 u16x4 __attribute__((ext_vector_type(4)));

#define NX 11796480   // B*T*D = 3840*3072
#define LDP 136       // padded LDS row (u16 elems) for P / Vt in temporal attn

__device__ __forceinline__ float bf2f(u16 u){ __bf16 h = __builtin_bit_cast(__bf16, u); return (float)h; }
__device__ __forceinline__ u16 f2bf(float f){ __bf16 h = (__bf16)f; return __builtin_bit_cast(u16, h); }

__device__ __forceinline__ void gload_lds16(const u16* g, u16* l){
  __builtin_amdgcn_global_load_lds((const __attribute__((address_space(1))) void*)g,
                                   (__attribute__((address_space(3))) void*)l, 16, 0, 0);
}

// ---------------- fused prep: zero BN accs + all fp32->bf16 conversions + QKV weight pack ----------------
__device__ __forceinline__ void cvt4seg(const float* __restrict__ in, u16* __restrict__ out, int i){
  float4v v = *(const float4v*)&in[i*4];
  u16x4 o;
  o[0]=f2bf(v[0]); o[1]=f2bf(v[1]); o[2]=f2bf(v[2]); o[3]=f2bf(v[3]);
  *(u16x4*)&out[i*4] = o;
}

// total items = 18432 + 2949120 + 2359296 + 2359296 + 196608 + 196608 + 2359296 = 10438656 = 40776*256
__global__ void k_prep(const float* __restrict__ src, u16* __restrict__ x_bf,
                       const float* __restrict__ wpt, u16* __restrict__ wptb,
                       const float* __restrict__ wps, u16* __restrict__ wpsb,
                       const float* __restrict__ w1,  u16* __restrict__ w1b,
                       const float* __restrict__ w2,  u16* __restrict__ w2b,
                       const float* __restrict__ wqt, const float* __restrict__ wkt,
                       const float* __restrict__ wvt, const float* __restrict__ wqs,
                       const float* __restrict__ wks, const float* __restrict__ wvs,
                       u16* __restrict__ wcat, float* __restrict__ accs){
  int i = blockIdx.x*256 + threadIdx.x;
  if (i < 18432){ accs[i] = 0.f; return; }
  i -= 18432;
  if (i < 2949120){ cvt4seg(src, x_bf, i); return; }
  i -= 2949120;
  if (i < 2359296){ cvt4seg(wpt, wptb, i); return; }
  i -= 2359296;
  if (i < 2359296){ cvt4seg(wps, wpsb, i); return; }
  i -= 2359296;
  if (i < 196608){ cvt4seg(w1, w1b, i); return; }
  i -= 196608;
  if (i < 196608){ cvt4seg(w2, w2b, i); return; }
  i -= 196608;
  // pack Wq_t|Wk_t|Wv_t|Wq_s|Wk_s|Wv_s into (J=24, N=768, K=128) row-major bf16
  int e = i & 127;
  int n = (i >> 7) % 768;
  int j = i / (768*128);
  float v;
  if (n < 512){
    int tn = n >> 7, hh = (n >> 4) & 7, dd = n & 15;
    const float* W = (tn==0)? wqt : (tn==1)? wkt : (tn==2)? wvt : wqs;  // (H,J,d,E)
    v = W[(((hh*24 + j)*16 + dd) << 7) + e];
  } else {
    int m = n - 512;
    int tn = m >> 7, hh = (m >> 4) & 7, dd = m & 15;
    const float* W = (tn==0)? wks : wvs;                                // (H,d,E)
    v = W[((hh*16 + dd) << 7) + e];
  }
  wcat[i] = f2bf(v);
}

// ---------------- MFMA GEMM core (BK=64): C[128,128] tile of A[M,K]*B[N,K]^T ----------------
// global_load_lds width=16 staging with XOR-swizzled source mapping (2-way max bank alias, free)
__device__ __forceinline__ void gemm_tile(const u16* __restrict__ Ab, int lda,
                                          const u16* __restrict__ Bb, int ldb,
                                          int K, f4 acc[4][4], u16* As, u16* Bs)
{
  const int tid  = threadIdx.x;
  const int lane = tid & 63;
  const int wid  = tid >> 6;
  const int waveM = (wid >> 1) * 64;
  const int waveN = (wid & 1) * 64;
  const int quad = lane >> 4;
  const int r16  = lane & 15;
  const int srow = tid >> 3;                       // 0..31
  const int gcol = ((tid & 7) ^ (srow & 7)) * 8;   // swizzled source column

  #pragma unroll
  for (int mt=0; mt<4; mt++)
    #pragma unroll
    for (int nt=0; nt<4; nt++)
      #pragma unroll
      for (int q=0; q<4; q++) acc[mt][nt][q] = 0.f;

  for (int k0 = 0; k0 < K; k0 += 64){
    __syncthreads();
    #pragma unroll
    for (int i=0; i<4; i++){
      int row = srow + i*32;
      gload_lds16(&Ab[(size_t)row*lda + k0 + gcol], As + wid*512 + i*2048);
      gload_lds16(&Bb[(size_t)row*ldb + k0 + gcol], Bs + wid*512 + i*2048);
    }
    __builtin_amdgcn_s_waitcnt(0);
    __syncthreads();
    #pragma unroll
    for (int kk=0; kk<2; kk++){
      bf16x8 af[4], bfr[4];
      const int soff = ((kk*4 + quad) ^ (r16 & 7)) * 8;   // swizzled read slot
      #pragma unroll
      for (int mt=0; mt<4; mt++)
        af[mt] = *(const bf16x8*)&As[(waveM + mt*16 + r16)*64 + soff];
      #pragma unroll
      for (int nt=0; nt<4; nt++)
        bfr[nt] = *(const bf16x8*)&Bs[(waveN + nt*16 + r16)*64 + soff];
      #pragma unroll
      for (int mt=0; mt<4; mt++)
        #pragma unroll
        for (int nt=0; nt<4; nt++)
          acc[mt][nt] = __builtin_amdgcn_mfma_f32_16x16x32_bf16(af[mt], bfr[nt], acc[mt][nt], 0, 0, 0);
    }
  }
  __syncthreads();
}

// ---------------- QKV GEMM: stage A once, loop 6 B-chunks of 128 (N=768 total) ----------------
__global__ __launch_bounds__(256)
void gemm_qkv(const u16* __restrict__ x, const u16* __restrict__ wcat,
              u16* __restrict__ qt, u16* __restrict__ kt, u16* __restrict__ vt,
              u16* __restrict__ qs, u16* __restrict__ ks, u16* __restrict__ vs)
{
  __shared__ __align__(16) u16 As[128*128];
  __shared__ __align__(16) u16 Bs[128*128];
  int m0 = blockIdx.x*128, j = blockIdx.y;
  const u16* Ab = x + (size_t)m0*3072 + j*128;
  const u16* Bbase = wcat + (size_t)j*98304;
  int tid = threadIdx.x, lane = tid & 63, wid = tid >> 6;
  int quad = lane >> 4, r16 = lane & 15;
  int srow16 = tid >> 4;                   // 0..15
  int cslot  = tid & 15;
  int gcol   = (cslot ^ srow16) * 8;       // swizzled source column

  #pragma unroll
  for (int it=0; it<8; it++){
    int row = srow16 + it*16;
    gload_lds16(&Ab[(size_t)row*3072 + gcol], As + tid*8 + it*2048);
  }

  int waveM = (wid>>1)*64, waveN = (wid&1)*64;

  for (int nc=0; nc<6; nc++){
    const u16* Bb = Bbase + (size_t)(nc*128)*128;
    #pragma unroll
    for (int it=0; it<8; it++){
      int row = srow16 + it*16;
      gload_lds16(&Bb[(size_t)row*128 + gcol], Bs + tid*8 + it*2048);
    }
    __builtin_amdgcn_s_waitcnt(0);
    __syncthreads();

    f4 acc[4][4];
    #pragma unroll
    for (int mt=0; mt<4; mt++)
      #pragma unroll
      for (int nt=0; nt<4; nt++)
        #pragma unroll
        for (int q=0; q<4; q++) acc[mt][nt][q] = 0.f;

    #pragma unroll
    for (int kk=0; kk<4; kk++){
      bf16x8 af[4], bfr[4];
      const int soff = ((kk*4 + quad) ^ r16) * 8;
      #pragma unroll
      for (int mt=0; mt<4; mt++)
        af[mt] = *(const bf16x8*)&As[(waveM + mt*16 + r16)*128 + soff];
      #pragma unroll
      for (int nt=0; nt<4; nt++)
        bfr[nt] = *(const bf16x8*)&Bs[(waveN + nt*16 + r16)*128 + soff];
      #pragma unroll
      for (int mt=0; mt<4; mt++)
        #pragma unroll
        for (int nt=0; nt<4; nt++)
          acc[mt][nt] = __builtin_amdgcn_mfma_f32_16x16x32_bf16(af[mt], bfr[nt], acc[mt][nt], 0, 0, 0);
    }

    #pragma unroll
    for (int mt=0; mt<4; mt++){
      #pragma unroll
      for (int reg=0; reg<4; reg++){
        int row = m0 + waveM + mt*16 + quad*4 + reg;   // bt index
        int b = row / 120, t = row % 120;
        #pragma unroll
        for (int nt=0; nt<4; nt++){
          int n = nc*128 + waveN + nt*16 + r16;
          u16 uv = f2bf(acc[mt][nt][reg]);
          if (n < 384){
            int tn = n >> 7, hh = (n >> 4) & 7, dd = n & 15;
            u16* base = (tn==0)? qt : (tn==1)? kt : vt;
            base[((((size_t)(b*8+hh)*24 + j)*120 + t) << 4) + dd] = uv;
          } else {
            int m2 = n - 384;
            int tn = m2 >> 7, hh = (m2 >> 4) & 7, dd = m2 & 15;
            u16* base = (tn==0)? qs : (tn==1)? ks : vs;
            base[((((size_t)row*8 + hh)*24 + j) << 4) + dd] = uv;
          }
        }
      }
    }
    __syncthreads();   // all waves done reading Bs before next chunk restages
  }
}

// ---------------- dual projection with fused BN stats ----------------
__global__ __launch_bounds__(256)
void gemm_proj_dual(const u16* __restrict__ A0, const u16* __restrict__ B0, const float* __restrict__ b0,
                    const u16* __restrict__ A1, const u16* __restrict__ B1, const float* __restrict__ b1v,
                    const u16* __restrict__ resb, u16* __restrict__ O0, u16* __restrict__ O1,
                    float* __restrict__ st0, float* __restrict__ st1)
{
  __shared__ __align__(16) u16 As[128*64];
  __shared__ __align__(16) u16 Bs[128*64];
  int m0 = blockIdx.x*128, n0 = blockIdx.y*128, z = blockIdx.z;
  const u16* A = z ? A1 : A0;
  const u16* B = z ? B1 : B0;
  const float* bias = z ? b1v : b0;
  u16* out = z ? O1 : O0;
  float* stp = z ? st1 : st0;
  f4 acc[4][4];
  gemm_tile(A + (size_t)m0*3072, 3072, B + (size_t)n0*3072, 3072, 3072, acc, As, Bs);
  int lane = threadIdx.x & 63, wid = threadIdx.x >> 6;
  int waveM = (wid>>1)*64, waveN = (wid&1)*64;
  int quad = lane>>4, r16 = lane&15;
  float s[4] = {0,0,0,0}, s2[4] = {0,0,0,0};
  #pragma unroll
  for (int mt=0; mt<4; mt++){
    #pragma unroll
    for (int reg=0; reg<4; reg++){
      int grow = m0 + waveM + mt*16 + quad*4 + reg;
      #pragma unroll
      for (int nt=0; nt<4; nt++){
        int gcol = n0 + waveN + nt*16 + r16;
        size_t idx = (size_t)grow*3072 + gcol;
        float v = acc[mt][nt][reg] + bias[gcol] + bf2f(resb[idx]);
        out[idx] = f2bf(v);
        s[nt] += v; s2[nt] += v*v;
      }
    }
  }
  #pragma unroll
  for (int nt=0; nt<4; nt++){
    float a = s[nt], b = s2[nt];
    a += __shfl_xor(a, 16); a += __shfl_xor(a, 32);
    b += __shfl_xor(b, 16); b += __shfl_xor(b, 32);
    if (quad == 0){
      int col = n0 + waveN + nt*16 + r16;
      atomicAdd(&stp[col], a);
      atomicAdd(&stp[3072 + col], b);
    }
  }
}

// ---------------- FF2 with fused BN stats ----------------
__global__ __launch_bounds__(256)
void gemm_ff2(const u16* __restrict__ A, const u16* __restrict__ B, const float* __restrict__ bias,
              const u16* __restrict__ resb, u16* __restrict__ out, float* __restrict__ stp)
{
  __shared__ __align__(16) u16 As[128*64];
  __shared__ __align__(16) u16 Bs[128*64];
  int m0 = blockIdx.x*128, n0 = blockIdx.y*128;
  f4 acc[4][4];
  gemm_tile(A + (size_t)m0*256, 256, B + (size_t)n0*256, 256, 256, acc, As, Bs);
  int lane = threadIdx.x & 63, wid = threadIdx.x >> 6;
  int waveM = (wid>>1)*64, waveN = (wid&1)*64;
  int quad = lane>>4, r16 = lane&15;
  float s[4] = {0,0,0,0}, s2[4] = {0,0,0,0};
  #pragma unroll
  for (int mt=0; mt<4; mt++){
    #pragma unroll
    for (int reg=0; reg<4; reg++){
      int grow = m0 + waveM + mt*16 + quad*4 + reg;
      #pragma unroll
      for (int nt=0; nt<4; nt++){
        int gcol = n0 + waveN + nt*16 + r16;
        size_t idx = (size_t)grow*3072 + gcol;
        float v = acc[mt][nt][reg] + bias[gcol] + bf2f(resb[idx]);
        out[idx] = f2bf(v);
        s[nt] += v; s2[nt] += v*v;
      }
    }
  }
  #pragma unroll
  for (int nt=0; nt<4; nt++){
    float a = s[nt], b = s2[nt];
    a += __shfl_xor(a, 16); a += __shfl_xor(a, 32);
    b += __shfl_xor(b, 16); b += __shfl_xor(b, 32);
    if (quad == 0){
      int col = n0 + waveN + nt*16 + r16;
      atomicAdd(&stp[col], a);
      atomicAdd(&stp[3072 + col], b);
    }
  }
}

// FF1: out bf16 = relu(A@B^T + bias)
__global__ __launch_bounds__(256)
void gemm_relu(const u16* __restrict__ A, const u16* __restrict__ B, int K, int N,
               const float* __restrict__ bias, u16* __restrict__ out)
{
  __shared__ __align__(16) u16 As[128*64];
  __shared__ __align__(16) u16 Bs[128*64];
  int m0 = blockIdx.x*128, n0 = blockIdx.y*128;
  f4 acc[4][4];
  gemm_tile(A + (size_t)m0*K, K, B + (size_t)n0*K, K, K, acc, As, Bs);
  int lane = threadIdx.x & 63, wid = threadIdx.x >> 6;
  int waveM = (wid>>1)*64, waveN = (wid&1)*64;
  int quad = lane>>4, r16 = lane&15;
  #pragma unroll
  for (int mt=0; mt<4; mt++){
    #pragma unroll
    for (int reg=0; reg<4; reg++){
      int grow = m0 + waveM + mt*16 + quad*4 + reg;
      #pragma unroll
      for (int nt=0; nt<4; nt++){
        int gcol = n0 + waveN + nt*16 + r16;
        float v = acc[mt][nt][reg] + bias[gcol];
        out[(size_t)grow*N + gcol] = f2bf(v > 0.f ? v : 0.f);
      }
    }
  }
}

// ---------------- merged attention: blocks [0,6144) temporal MFMA, [6144,9984) spatial ----------------
__global__ __launch_bounds__(256)
void attn_both(const u16* __restrict__ qt, const u16* __restrict__ kt,
               const u16* __restrict__ vt, u16* __restrict__ ta,
               const u16* __restrict__ qsp, const u16* __restrict__ ksp,
               const u16* __restrict__ vsp, u16* __restrict__ sa)
{
  __shared__ __align__(16) char smem[39168];
  int tid = threadIdx.x, lane = tid & 63, wid = tid >> 6;
  int quad = lane >> 4, r16 = lane & 15;

  if (blockIdx.x < 6144){
    // ---- temporal: one block per (b,h,j), T=120 pad 128, d=16 pad 32 ----
    u16* P  = (u16*)smem;             // 128*LDP
    u16* Vt = (u16*)(smem + 34816);   // 16*LDP
    int blk = blockIdx.x;
    int b = blk / 192;
    int rem = blk % 192;
    int h = rem / 24, j = rem % 24;
    const u16* qb = qt + (size_t)blk*1920;
    const u16* kb = kt + (size_t)blk*1920;
    const u16* vb = vt + (size_t)blk*1920;

    for (int e = tid; e < 1920; e += 256){
      int s = e >> 4, dd = e & 15;
      Vt[dd*LDP + s] = vb[e];
    }
    if (tid < 128){ int dd = tid >> 3, s = 120 + (tid & 7); Vt[dd*LDP + s] = 0; }
    __syncthreads();

    bf16x8 zv;
    #pragma unroll
    for (int i=0;i<8;i++) zv[i] = (__bf16)0.f;

    const int m0 = wid * 32;
    bf16x8 qf[2];
    #pragma unroll
    for (int mt=0; mt<2; mt++){
      int row = m0 + mt*16 + r16; if (row > 119) row = 119;
      qf[mt] = (quad < 2) ? *(const bf16x8*)&qb[row*16 + (quad&1)*8] : zv;
    }

    f4 S[2][8];
    #pragma unroll
    for (int nt=0; nt<8; nt++){
      int col = nt*16 + r16; int colc = col > 119 ? 119 : col;
      bf16x8 kf = (quad < 2) ? *(const bf16x8*)&kb[colc*16 + (quad&1)*8] : zv;
      #pragma unroll
      for (int mt=0; mt<2; mt++){
        f4 zz = {0.f, 0.f, 0.f, 0.f};
        S[mt][nt] = __builtin_amdgcn_mfma_f32_16x16x32_bf16(qf[mt], kf, zz, 0, 0, 0);
      }
    }

    #pragma unroll
    for (int mt=0; mt<2; mt++)
      #pragma unroll
      for (int nt=0; nt<8; nt++)
        #pragma unroll
        for (int reg=0; reg<4; reg++){
          int c = nt*16 + r16;
          int r = m0 + mt*16 + quad*4 + reg;
          float v = S[mt][nt][reg] * 0.25f;
          S[mt][nt][reg] = (c > r || c >= 120) ? -1e30f : v;
        }

    float Zr[2][4];
    #pragma unroll
    for (int mt=0; mt<2; mt++)
      #pragma unroll
      for (int reg=0; reg<4; reg++){
        float m = -1e30f;
        #pragma unroll
        for (int nt=0; nt<8; nt++) m = fmaxf(m, S[mt][nt][reg]);
        #pragma unroll
        for (int off=1; off<16; off<<=1) m = fmaxf(m, __shfl_xor(m, off, 16));
        float z = 0.f;
        #pragma unroll
        for (int nt=0; nt<8; nt++){
          float e = __expf(S[mt][nt][reg] - m);
          S[mt][nt][reg] = e;
          z += e;
        }
        #pragma unroll
        for (int off=1; off<16; off<<=1) z += __shfl_xor(z, off, 16);
        Zr[mt][reg] = z;
      }

    #pragma unroll
    for (int mt=0; mt<2; mt++)
      #pragma unroll
      for (int nt=0; nt<8; nt++)
        #pragma unroll
        for (int reg=0; reg<4; reg++)
          P[(m0 + mt*16 + quad*4 + reg)*LDP + nt*16 + r16] = f2bf(S[mt][nt][reg]);
    __syncthreads();

    f4 O[2];
    #pragma unroll
    for (int mt=0; mt<2; mt++){ O[mt][0]=0.f; O[mt][1]=0.f; O[mt][2]=0.f; O[mt][3]=0.f; }
    #pragma unroll
    for (int kt8=0; kt8<4; kt8++){
      bf16x8 vf = *(const bf16x8*)&Vt[r16*LDP + kt8*32 + quad*8];
      #pragma unroll
      for (int mt=0; mt<2; mt++){
        bf16x8 pf = *(const bf16x8*)&P[(m0 + mt*16 + r16)*LDP + kt8*32 + quad*8];
        O[mt] = __builtin_amdgcn_mfma_f32_16x16x32_bf16(pf, vf, O[mt], 0, 0, 0);
      }
    }

    #pragma unroll
    for (int mt=0; mt<2; mt++)
      #pragma unroll
      for (int reg=0; reg<4; reg++){
        int r = m0 + mt*16 + quad*4 + reg;
        if (r < 120){
          size_t idx = (size_t)(b*120 + r)*3072 + h*384 + j*16 + r16;
          ta[idx] = f2bf(O[mt][reg] / Zr[mt][reg]);
        }
      }
  } else {
    // ---- spatial: one block per (b,t); threads 0..191 = (h,j); softmax over 24 joints ----
    float* Ks = (float*)smem;            // 3072
    float* Vs = (float*)(smem + 12288);  // 3072
    int bt = blockIdx.x - 6144;
    size_t base = (size_t)bt * 3072;
    for (int c = tid; c < 384; c += 256){
      bf16x8 kv = *(const bf16x8*)&ksp[base + c*8];
      bf16x8 vv = *(const bf16x8*)&vsp[base + c*8];
      #pragma unroll
      for (int i=0;i<8;i++){ Ks[c*8+i] = (float)kv[i]; Vs[c*8+i] = (float)vv[i]; }
    }
    __syncthreads();
    if (tid < 192){
      int h = tid / 24, j = tid % 24;
      float q[16];
      #pragma unroll
      for (int d2=0; d2<16; d2++) q[d2] = bf2f(qsp[base + h*384 + j*16 + d2]);
      float sc[24], mx = -1e30f;
      #pragma unroll
      for (int kk=0; kk<24; kk++){
        float dot = 0.f;
        #pragma unroll
        for (int d2=0; d2<16; d2++) dot += q[d2]*Ks[h*384 + kk*16 + d2];
        sc[kk] = dot * 0.25f;
        mx = fmaxf(mx, sc[kk]);
      }
      float Z = 0.f, acc[16];
      #pragma unroll
      for (int d2=0; d2<16; d2++) acc[d2] = 0.f;
      #pragma unroll
      for (int kk=0; kk<24; kk++){
        float w = __expf(sc[kk] - mx);
        Z += w;
        #pragma unroll
        for (int d2=0; d2<16; d2++) acc[d2] += w*Vs[h*384 + kk*16 + d2];
      }
      float inv = 1.f / Z;
      #pragma unroll
      for (int d2=0; d2<16; d2++) sa[base + h*384 + j*16 + d2] = f2bf(acc[d2]*inv);
    }
  }
}

// ---------------- batchnorm ----------------
// blocks 0..11: temporal coefs; 12..23: spatial coefs
__global__ void bn_coef2(const float* __restrict__ accT, const float* __restrict__ gT,
                         const float* __restrict__ bT, float* __restrict__ cT,
                         const float* __restrict__ accS, const float* __restrict__ gS,
                         const float* __restrict__ bS, float* __restrict__ cS){
  int isS = blockIdx.x >= 12;
  const float* acc = isS ? accS : accT;
  const float* g   = isS ? gS : gT;
  const float* b   = isS ? bS : bT;
  float* coef      = isS ? cS : cT;
  int c = (blockIdx.x % 12)*256 + threadIdx.x;
  float mean = acc[c] * (1.f/3840.f);
  float var  = acc[3072+c] * (1.f/3840.f) - mean*mean;
  float sc = g[c] * rsqrtf(var + 1e-5f);
  coef[c] = sc;
  coef[3072+c] = b[c] - mean*sc;
}

__global__ void bn_coef(const float* __restrict__ acc, const float* __restrict__ g,
                        const float* __restrict__ b, float* __restrict__ coef){
  int c = blockIdx.x*256 + threadIdx.x;
  float mean = acc[c] * (1.f/3840.f);
  float var  = acc[3072+c] * (1.f/3840.f) - mean*mean;
  float sc = g[c] * rsqrtf(var + 1e-5f);
  coef[c] = sc;
  coef[3072+c] = b[c] - mean*sc;
}

// att = BN_t(Yt) + BN_s(Ys), vectorized x4  (channel = (i*4) mod 3072 — NOT a pow2 mask!)
__global__ void bn_apply2(const u16* __restrict__ Ytb, const u16* __restrict__ Ysb,
                          const float* __restrict__ ct, const float* __restrict__ cs,
                          u16* __restrict__ attB){
  int i = blockIdx.x*256 + threadIdx.x;     // < NX/4
  int c = (i*4) % 3072;
  u16x4 yt = *(const u16x4*)&Ytb[i*4];
  u16x4 ys = *(const u16x4*)&Ysb[i*4];
  u16x4 o;
  #pragma unroll
  for (int k=0;k<4;k++){
    float a = bf2f(yt[k])*ct[c+k] + ct[3072+c+k] + bf2f(ys[k])*cs[c+k] + cs[3072+c+k];
    o[k] = f2bf(a);
  }
  *(u16x4*)&attB[i*4] = o;
}

__global__ void bn_out(const u16* __restrict__ Yfb, const float* __restrict__ cf,
                       float* __restrict__ out){
  int i = blockIdx.x*256 + threadIdx.x;     // < NX/4
  int c = (i*4) % 3072;
  u16x4 yf = *(const u16x4*)&Yfb[i*4];
  float4v o;
  #pragma unroll
  for (int k=0;k<4;k++) o[k] = bf2f(yf[k])*cf[c+k] + cf[3072+c+k];
  *(float4v*)&out[i*4] = o;
}

// ---------------- launch ----------------
extern "C" void kernel_launch(void* const* d_in, const int* in_sizes, int n_in,
                              void* d_out, int out_size, void* d_ws, size_t ws_size,
                              hipStream_t stream)
{
  const float* src  = (const float*)d_in[0];
  const float* Wq_t = (const float*)d_in[1];
  const float* Wk_t = (const float*)d_in[2];
  const float* Wv_t = (const float*)d_in[3];
  const float* Wp_t = (const float*)d_in[4];
  const float* bp_t = (const float*)d_in[5];
  const float* g_t  = (const float*)d_in[6];
  const float* b_t  = (const float*)d_in[7];
  const float* Wq_s = (const float*)d_in[8];
  const float* Wk_s = (const float*)d_in[9];
  const float* Wv_s = (const float*)d_in[10];
  const float* Wp_s = (const float*)d_in[11];
  const float* bp_s = (const float*)d_in[12];
  const float* g_s  = (const float*)d_in[13];
  const float* b_s  = (const float*)d_in[14];
  const float* W1   = (const float*)d_in[15];
  const float* b1   = (const float*)d_in[16];
  const float* W2   = (const float*)d_in[17];
  const float* b2   = (const float*)d_in[18];
  const float* g_f  = (const float*)d_in[19];
  const float* b_f  = (const float*)d_in[20];

  char* ws = (char*)d_ws;
  u16* x_bf  = (u16*)(ws + 0ull);
  u16* wptb  = (u16*)(ws + 23592960ull);
  u16* wpsb  = (u16*)(ws + 42467328ull);
  u16* w1b   = (u16*)(ws + 61341696ull);
  u16* w2b   = (u16*)(ws + 62914560ull);
  u16* wcat  = (u16*)(ws + 64487424ull);
  u16* qt    = (u16*)(ws + 69206016ull);
  u16* kt    = qt + NX;
  u16* vt    = kt + NX;
  u16* qs    = vt + NX;
  u16* ks    = qs + NX;
  u16* vs    = ks + NX;
  u16* tab   = (u16*)(ws + 210763776ull);
  u16* sab   = (u16*)(ws + 234356736ull);
  float* accT = (float*)(ws + 257949696ull);
  float* accS = accT + 6144;
  float* accF = accS + 6144;
  float* cT   = accF + 6144;
  float* cS   = cT + 6144;
  float* cF   = cS + 6144;
  // bf16 aliases over dead regions
  u16* Ytb  = qt;   // dead after attention
  u16* Ysb  = kt;
  u16* attB = vt;
  u16* Yfb  = qs;
  u16* h1   = wcat; // dead after gemm_qkv
  float* out = (float*)d_out;

  // 1. fused prep (zero accs + conversions + weight pack)
  k_prep<<<40776, 256, 0, stream>>>(src, x_bf, Wp_t, wptb, Wp_s, wpsb, W1, w1b, W2, w2b,
                                    Wq_t, Wk_t, Wv_t, Wq_s, Wk_s, Wv_s, wcat, accT);
  // 2. QKV projections (per joint; A staged once, 6 B-chunks)
  gemm_qkv<<<dim3(30,24), 256, 0, stream>>>(x_bf, wcat, qt, kt, vt, qs, ks, vs);
  // 3. both attentions in one launch
  attn_both<<<9984, 256, 0, stream>>>(qt, kt, vt, tab, qs, ks, vs, sab);
  // 4. output projections + residual + fused BN stats
  gemm_proj_dual<<<dim3(30,24,2), 256, 0, stream>>>(tab, wptb, bp_t, sab, wpsb, bp_s,
                                                    x_bf, Ytb, Ysb, accT, accS);
  // 5. BN coefs (t+s) + fused apply
  bn_coef2<<<24, 256, 0, stream>>>(accT, g_t, b_t, cT, accS, g_s, b_s, cS);
  bn_apply2<<<11520, 256, 0, stream>>>(Ytb, Ysb, cT, cS, attB);
  // 6. feed-forward
  gemm_relu<<<dim3(30,2), 256, 0, stream>>>(attB, w1b, 3072, 256, b1, h1);
  gemm_ff2<<<dim3(30,24), 256, 0, stream>>>(h1, w2b, b2, attB, Yfb, accF);
  // 7. final BN
  bn_coef<<<12, 256, 0, stream>>>(accF, g_f, b_f, cF);
  bn_out<<<11520, 256, 0, stream>>>(Yfb, cF, out);
}